// Round 4
// baseline (2705.322 us; speedup 1.0000x reference)
//
#include <hip/hip_runtime.h>
#include <hip/hip_bf16.h>
#include <cmath>

#define NODES 150000
#define DIM 64
#define EDGES 1200000
#define NREL 32
#define NLAYERS 2
#define NND (NODES*DIM)

typedef __hip_bfloat16 bf16;

__device__ __forceinline__ float b2f(bf16 v){ return __bfloat162float(v); }

// monotone float<->uint key for atomicMax over signed floats
__device__ __forceinline__ unsigned f2key(float f){
  unsigned b = __float_as_uint(f);
  return (b & 0x80000000u) ? ~b : (b | 0x80000000u);
}
__device__ __forceinline__ float key2f(unsigned k){
  unsigned b = (k & 0x80000000u) ? (k & 0x7fffffffu) : ~k;
  return __uint_as_float(b);
}

// sentinel: encode ws_size (MB) into every output element (tripwire only)
__global__ void __launch_bounds__(256) k_sentinel(float* __restrict__ out, float wsmb){
  int i = blockIdx.x*256 + threadIdx.x;
  if (i < NND) out[i] = wsmb;
}

// convert node_emb f32 -> bf16 working buffer
__global__ void __launch_bounds__(256) k_init(const float* __restrict__ node, bf16* __restrict__ x){
  int i = blockIdx.x*256 + threadIdx.x;
  if (i < NND) x[i] = __float2bfloat16(node[i]);
}

// s_rel[r] = rel[r] . (W_r @ a_rel); zero the global-max key
__global__ void k_rel(const float* __restrict__ Wr_l, const float* __restrict__ a_l,
                      const float* __restrict__ rel_l, float* __restrict__ s_rel,
                      unsigned* __restrict__ gmax){
  __shared__ float w[DIM];
  int t = threadIdx.x; // 64 threads
  float s = 0.f;
  for (int j = 0; j < DIM; j++) s += Wr_l[t*DIM + j] * a_l[DIM + j];
  w[t] = s;
  __syncthreads();
  if (t < NREL){
    float r = 0.f;
    for (int k = 0; k < DIM; k++) r += rel_l[t*DIM + k] * w[k];
    s_rel[t] = r;
  }
  if (t == 0) *gmax = 0u;
}

// xt = x @ W (bf16 -> bf16, in-place safe: each row private to one wave)
// s_src = xt . a[0:64], s_dst = xt . a[128:192]; also zeroes count[].
__global__ void __launch_bounds__(256) k_gemm(const bf16* xin, bf16* xt,
                                              const float* __restrict__ W_l,
                                              const float* __restrict__ a_l,
                                              float* __restrict__ s_src_a,
                                              float* __restrict__ s_dst_a,
                                              int* __restrict__ count){
  int tid = threadIdx.x;
  int tid0 = blockIdx.x*256 + tid;
  for (int i = tid0; i < NODES; i += gridDim.x*256) count[i] = 0;

  __shared__ float Ws[DIM*DIM];
  for (int i = tid; i < DIM*DIM; i += 256) Ws[i] = W_l[i];
  __syncthreads();
  int lane = tid & 63;
  int wid  = tid >> 6;
  float asrc = a_l[lane];
  float adst = a_l[2*DIM + lane];
  int gw = blockIdx.x*4 + wid;
  int nw = gridDim.x*4;
  for (int row = gw; row < NODES; row += nw){
    float xv = b2f(xin[row*DIM + lane]);
    float accv = 0.f;
    #pragma unroll
    for (int k = 0; k < DIM; k++)
      accv = fmaf(__shfl(xv, k, 64), Ws[k*DIM + lane], accv);
    xt[row*DIM + lane] = __float2bfloat16(accv);
    float p = accv * asrc, q = accv * adst;
    #pragma unroll
    for (int off = 32; off > 0; off >>= 1){
      p += __shfl_xor(p, off, 64);
      q += __shfl_xor(q, off, 64);
    }
    if (lane == 0){ s_src_a[row] = p; s_dst_a[row] = q; }
  }
}

// per-edge score+leakyrelu -> e16 (bf16), histogram count[dst]++, global max
__global__ void __launch_bounds__(256) k_score(const int* __restrict__ src, const int* __restrict__ dst,
                                               const int* __restrict__ et,
                                               const float* __restrict__ s_src_a,
                                               const float* __restrict__ s_dst_a,
                                               const float* __restrict__ s_rel,
                                               bf16* __restrict__ e16,
                                               int* __restrict__ count,
                                               unsigned* __restrict__ gmax){
  int tid0 = blockIdx.x*256 + threadIdx.x;
  int stride = gridDim.x*256;
  float lmax = -INFINITY;
  for (int e = tid0; e < EDGES; e += stride){
    float v = s_src_a[src[e]] + s_rel[et[e]] + s_dst_a[dst[e]];
    v = v > 0.f ? v : 0.2f*v;
    bf16 vb = __float2bfloat16(v);
    e16[e] = vb;
    lmax = fmaxf(lmax, b2f(vb));   // max of ROUNDED value so e-m<=0 exactly
    atomicAdd(&count[dst[e]], 1);
  }
  #pragma unroll
  for (int off = 32; off > 0; off >>= 1) lmax = fmaxf(lmax, __shfl_xor(lmax, off, 64));
  if ((threadIdx.x & 63) == 0) atomicMax(gmax, f2key(lmax));
}

// single-block exclusive scan of count -> row_ptr (+copy to cursor)
__global__ void __launch_bounds__(1024) k_scan(const int* __restrict__ count,
                                               int* __restrict__ row_ptr,
                                               int* __restrict__ cursor){
  __shared__ int s[1024];
  int tid = threadIdx.x;
  int base = 0;
  for (int chunk = 0; chunk < NODES; chunk += 1024){
    int i = chunk + tid;
    int c = (i < NODES) ? count[i] : 0;
    __syncthreads();
    s[tid] = c;
    __syncthreads();
    for (int off = 1; off < 1024; off <<= 1){
      int t = (tid >= off) ? s[tid - off] : 0;
      __syncthreads();
      s[tid] += t;
      __syncthreads();
    }
    int excl = s[tid] - c;
    if (i < NODES){ row_ptr[i] = base + excl; cursor[i] = base + excl; }
    base += s[1023];
  }
  if (tid == 0) row_ptr[NODES] = base;
}

// scatter edges into CSR order: colw[p] = (src, exp(e-m))
__global__ void __launch_bounds__(256) k_scatter(const int* __restrict__ src, const int* __restrict__ dst,
                                                 const bf16* __restrict__ e16,
                                                 int* __restrict__ cursor,
                                                 int2* __restrict__ colw,
                                                 const unsigned* __restrict__ gmax){
  float m = key2f(*gmax);
  int tid0 = blockIdx.x*256 + threadIdx.x;
  int stride = gridDim.x*256;
  for (int e = tid0; e < EDGES; e += stride){
    int d = dst[e];
    int p = atomicAdd(&cursor[d], 1);
    int2 cw;
    cw.x = src[e];
    cw.y = __float_as_int(expf(b2f(e16[e]) - m));
    colw[p] = cw;
  }
}

// one wave per dst row: h = sum(w*xt[col]) / (sum w + 1e-10); ELU; L2-norm;
// write x_next (bf16); acc into d_out (f32): mode0 store, mode1 add. No atomics.
__global__ void __launch_bounds__(256) k_agg(const int* __restrict__ row_ptr,
                                             const int2* __restrict__ colw,
                                             const bf16* __restrict__ xt,
                                             bf16* __restrict__ xnext,
                                             float* __restrict__ outacc, int mode){
  int lane = threadIdx.x & 63;
  int gw = blockIdx.x*4 + (threadIdx.x >> 6);
  int nw = gridDim.x*4;
  for (int row = gw; row < NODES; row += nw){
    int beg = row_ptr[row], end = row_ptr[row+1];
    float hacc = 0.f, wsum = 0.f;
    for (int j = beg; j < end; j++){
      int2 cw = colw[j];                            // wave-uniform 8B broadcast
      float wgt = __int_as_float(cw.y);
      float xv = b2f(xt[(size_t)cw.x*DIM + lane]);  // coalesced 128B gather
      hacc = fmaf(wgt, xv, hacc);
      wsum += wgt;
    }
    float v = hacc / (wsum + 1e-10f);
    v = v > 0.f ? v : expm1f(v);
    float ss = v*v;
    #pragma unroll
    for (int off = 32; off > 0; off >>= 1) ss += __shfl_xor(ss, off, 64);
    float n = fmaxf(sqrtf(ss), 1e-12f);
    float x = v / n;
    int i = row*DIM + lane;
    xnext[i] = __float2bfloat16(x);
    if (mode == 0) outacc[i] = x;
    else           outacc[i] += x;
  }
}

// out = (node_emb + acc) / 3   (all f32)
__global__ void __launch_bounds__(256) k_final(const float* __restrict__ node, float* outacc){
  int i = blockIdx.x*256 + threadIdx.x;
  if (i < NND) outacc[i] = (node[i] + outacc[i]) * (1.f/3.f);
}

extern "C" void kernel_launch(void* const* d_in, const int* in_sizes, int n_in,
                              void* d_out, int out_size, void* d_ws, size_t ws_size,
                              hipStream_t stream){
  const float* node = (const float*)d_in[0];
  const float* W    = (const float*)d_in[1];
  const float* Wr   = (const float*)d_in[2];
  const float* a    = (const float*)d_in[3];
  const float* rel  = (const float*)d_in[4];
  const int*   ei   = (const int*)d_in[5];
  const int*   et   = (const int*)d_in[6];
  const int* src = ei;
  const int* dst = ei + EDGES;
  float* out = (float*)d_out;

  // ---- workspace layout (53.4 MB; previous round proved ws_size >= this) ----
  char* w = (char*)d_ws;
  size_t off = 0;
  bf16* B  = (bf16*)(w + off); off += (size_t)NND*2;          // 19.2 MB  x/xt ping
  bf16* XN = (bf16*)(w + off); off += (size_t)NND*2;          // 19.2 MB  x pong
  int2* colw = (int2*)(w + off); off += (size_t)EDGES*8;      //  9.6 MB  CSR (col, weight)
  int* row_ptr = (int*)(w + off); off += (size_t)(NODES+1)*4; //  0.6 MB
  int* cursor  = (int*)(w + off); off += (size_t)NODES*4;     //  0.6 MB
  int* count   = (int*)(w + off); off += (size_t)NODES*4;     //  0.6 MB
  bf16* e16 = (bf16*)(w + off); off += (size_t)EDGES*2;       //  2.4 MB
  float* s_src = (float*)(w + off); off += (size_t)NODES*4;   //  0.6 MB
  float* s_dst = (float*)(w + off); off += (size_t)NODES*4;   //  0.6 MB
  float* s_rel = (float*)(w + off); off += 128;
  unsigned* gmax = (unsigned*)(w + off); off += 4;

  if (ws_size < off){
    k_sentinel<<<(NND + 255)/256, 256, 0, stream>>>(out, (float)ws_size * 1e-6f);
    return;
  }

  k_init<<<(NND + 255)/256, 256, 0, stream>>>(node, B);
  for (int l = 0; l < NLAYERS; l++){
    const float* W_l   = W   + l*DIM*DIM;
    const float* Wr_l  = Wr  + l*DIM*DIM;
    const float* a_l   = a   + l*3*DIM;
    const float* rel_l = rel + l*NREL*DIM;
    bf16* xcur  = (l == 0) ? B : XN;   // transformed in-place to xt
    bf16* xnext = (l == 0) ? XN : B;
    k_rel    <<<1, 64, 0, stream>>>(Wr_l, a_l, rel_l, s_rel, gmax);
    k_gemm   <<<2048, 256, 0, stream>>>(xcur, xcur, W_l, a_l, s_src, s_dst, count);
    k_score  <<<4096, 256, 0, stream>>>(src, dst, et, s_src, s_dst, s_rel, e16, count, gmax);
    k_scan   <<<1, 1024, 0, stream>>>(count, row_ptr, cursor);
    k_scatter<<<4096, 256, 0, stream>>>(src, dst, e16, cursor, colw, gmax);
    k_agg    <<<2048, 256, 0, stream>>>(row_ptr, colw, xcur, xnext, out, l);
  }
  k_final<<<(NND + 255)/256, 256, 0, stream>>>(node, out);
}

// Round 5
// 1031.839 us; speedup vs baseline: 2.6218x; 2.6218x over previous
//
#include <hip/hip_runtime.h>
#include <hip/hip_bf16.h>
#include <cmath>

#define NODES 150000
#define DIM 64
#define EDGES 1200000
#define NREL 32
#define NLAYERS 2
#define NND (NODES*DIM)

typedef __hip_bfloat16 bf16;

__device__ __forceinline__ float b2f(bf16 v){ return __bfloat162float(v); }

// sentinel: encode ws_size (MB) into output (tripwire only)
__global__ void __launch_bounds__(256) k_sentinel(float* __restrict__ out, float wsmb){
  int i = blockIdx.x*256 + threadIdx.x;
  if (i < NND) out[i] = wsmb;
}

// node f32 -> bf16 working buffer; zero count[]
__global__ void __launch_bounds__(256) k_init(const float* __restrict__ node, bf16* __restrict__ x,
                                              int* __restrict__ count){
  int i = blockIdx.x*256 + threadIdx.x;
  if (i < NND) x[i] = __float2bfloat16(node[i]);
  if (i < NODES) count[i] = 0;
}

// one-time: histogram count[dst]++
__global__ void __launch_bounds__(256) k_hist(const int* __restrict__ dst, int* __restrict__ count){
  int tid0 = blockIdx.x*256 + threadIdx.x;
  int stride = gridDim.x*256;
  for (int e = tid0; e < EDGES; e += stride)
    atomicAdd(&count[dst[e]], 1);
}

// one-time: single-block exclusive scan count -> row_ptr (+cursor copy)
__global__ void __launch_bounds__(1024) k_scan(const int* __restrict__ count,
                                               int* __restrict__ row_ptr,
                                               int* __restrict__ cursor){
  __shared__ int s[1024];
  int tid = threadIdx.x;
  int base = 0;
  for (int chunk = 0; chunk < NODES; chunk += 1024){
    int i = chunk + tid;
    int c = (i < NODES) ? count[i] : 0;
    __syncthreads();
    s[tid] = c;
    __syncthreads();
    for (int off = 1; off < 1024; off <<= 1){
      int t = (tid >= off) ? s[tid - off] : 0;
      __syncthreads();
      s[tid] += t;
      __syncthreads();
    }
    int excl = s[tid] - c;
    if (i < NODES){ row_ptr[i] = base + excl; cursor[i] = base + excl; }
    base += s[1023];
  }
  if (tid == 0) row_ptr[NODES] = base;
}

// one-time: scatter packed (src | et<<18) into CSR slots
__global__ void __launch_bounds__(256) k_build(const int* __restrict__ src, const int* __restrict__ dst,
                                               const int* __restrict__ et,
                                               int* __restrict__ cursor,
                                               unsigned* __restrict__ cse){
  int tid0 = blockIdx.x*256 + threadIdx.x;
  int stride = gridDim.x*256;
  for (int e = tid0; e < EDGES; e += stride){
    int p = atomicAdd(&cursor[dst[e]], 1);
    cse[p] = (unsigned)src[e] | ((unsigned)et[e] << 18);
  }
}

// per layer: s_rel[r] = rel[r] . (W_r @ a_rel)
__global__ void k_rel(const float* __restrict__ Wr_l, const float* __restrict__ a_l,
                      const float* __restrict__ rel_l, float* __restrict__ s_rel){
  __shared__ float w[DIM];
  int t = threadIdx.x; // 64 threads
  float s = 0.f;
  for (int j = 0; j < DIM; j++) s += Wr_l[t*DIM + j] * a_l[DIM + j];
  w[t] = s;
  __syncthreads();
  if (t < NREL){
    float r = 0.f;
    for (int k = 0; k < DIM; k++) r += rel_l[t*DIM + k] * w[k];
    s_rel[t] = r;
  }
}

// per layer: xt = x @ W (bf16->bf16, in-place safe; row private to one wave)
// s_src = xt . a[0:64], s_dst = xt . a[128:192]
__global__ void __launch_bounds__(256) k_gemm(const bf16* xin, bf16* xt,
                                              const float* __restrict__ W_l,
                                              const float* __restrict__ a_l,
                                              float* __restrict__ s_src_a,
                                              float* __restrict__ s_dst_a){
  __shared__ float Ws[DIM*DIM];
  int tid = threadIdx.x;
  for (int i = tid; i < DIM*DIM; i += 256) Ws[i] = W_l[i];
  __syncthreads();
  int lane = tid & 63;
  int wid  = tid >> 6;
  float asrc = a_l[lane];
  float adst = a_l[2*DIM + lane];
  int gw = blockIdx.x*4 + wid;
  int nw = gridDim.x*4;
  for (int row = gw; row < NODES; row += nw){
    float xv = b2f(xin[row*DIM + lane]);
    float accv = 0.f;
    #pragma unroll
    for (int k = 0; k < DIM; k++)
      accv = fmaf(__shfl(xv, k, 64), Ws[k*DIM + lane], accv);
    xt[row*DIM + lane] = __float2bfloat16(accv);
    float p = accv * asrc, q = accv * adst;
    #pragma unroll
    for (int off = 32; off > 0; off >>= 1){
      p += __shfl_xor(p, off, 64);
      q += __shfl_xor(q, off, 64);
    }
    if (lane == 0){ s_src_a[row] = p; s_dst_a[row] = q; }
  }
}

// per layer, one wave per dst row: scores inline (softmax max-shift dropped —
// exactly invariant), h = sum(w*xt[src])/(sum w + 1e-10); ELU; L2-norm;
// write x_next (bf16); acc into d_out (f32): mode0 store, mode1 add.
__global__ void __launch_bounds__(256) k_agg(const int* __restrict__ row_ptr,
                                             const unsigned* __restrict__ cse,
                                             const float* __restrict__ s_src_a,
                                             const float* __restrict__ s_dst_a,
                                             const float* __restrict__ s_rel,
                                             const bf16* __restrict__ xt,
                                             bf16* __restrict__ xnext,
                                             float* __restrict__ outacc, int mode){
  int lane = threadIdx.x & 63;
  int gw = blockIdx.x*4 + (threadIdx.x >> 6);
  int nw = gridDim.x*4;
  for (int row = gw; row < NODES; row += nw){
    int beg = row_ptr[row], end = row_ptr[row+1];
    float sdst = s_dst_a[row];
    float hacc = 0.f, wsum = 0.f;
    for (int j = beg; j < end; j++){
      unsigned pk = cse[j];                 // wave-uniform 4B broadcast
      int s = (int)(pk & 0x3FFFFu);
      int r = (int)(pk >> 18);
      float e = s_src_a[s] + s_rel[r] + sdst;  // uniform scalar loads
      e = e > 0.f ? e : 0.2f*e;
      float wgt = __expf(e);
      float xv = b2f(xt[(size_t)s*DIM + lane]);  // coalesced 128B row gather
      hacc = fmaf(wgt, xv, hacc);
      wsum += wgt;
    }
    float v = hacc / (wsum + 1e-10f);
    v = v > 0.f ? v : expm1f(v);
    float ss = v*v;
    #pragma unroll
    for (int off = 32; off > 0; off >>= 1) ss += __shfl_xor(ss, off, 64);
    float n = fmaxf(sqrtf(ss), 1e-12f);
    float x = v / n;
    int i = row*DIM + lane;
    xnext[i] = __float2bfloat16(x);
    if (mode == 0) outacc[i] = x;
    else           outacc[i] += x;
  }
}

// out = (node_emb + acc) / 3   (f32)
__global__ void __launch_bounds__(256) k_final(const float* __restrict__ node, float* outacc){
  int i = blockIdx.x*256 + threadIdx.x;
  if (i < NND) outacc[i] = (node[i] + outacc[i]) * (1.f/3.f);
}

extern "C" void kernel_launch(void* const* d_in, const int* in_sizes, int n_in,
                              void* d_out, int out_size, void* d_ws, size_t ws_size,
                              hipStream_t stream){
  const float* node = (const float*)d_in[0];
  const float* W    = (const float*)d_in[1];
  const float* Wr   = (const float*)d_in[2];
  const float* a    = (const float*)d_in[3];
  const float* rel  = (const float*)d_in[4];
  const int*   ei   = (const int*)d_in[5];
  const int*   et   = (const int*)d_in[6];
  const int* src = ei;
  const int* dst = ei + EDGES;
  float* out = (float*)d_out;

  // ---- workspace layout (~46 MB; round 4 proved >= 53.4 MB available) ----
  char* w = (char*)d_ws;
  size_t off = 0;
  bf16* B  = (bf16*)(w + off); off += (size_t)NND*2;             // 19.2 MB x/xt ping
  bf16* XN = (bf16*)(w + off); off += (size_t)NND*2;             // 19.2 MB x pong
  unsigned* cse = (unsigned*)(w + off); off += (size_t)EDGES*4;  //  4.8 MB CSR packed (src|et<<18)
  int* row_ptr = (int*)(w + off); off += (size_t)(NODES+1)*4;    //  0.6 MB
  int* cursor  = (int*)(w + off); off += (size_t)NODES*4;        //  0.6 MB
  int* count   = (int*)(w + off); off += (size_t)NODES*4;        //  0.6 MB
  float* s_src = (float*)(w + off); off += (size_t)NODES*4;      //  0.6 MB
  float* s_dst = (float*)(w + off); off += (size_t)NODES*4;      //  0.6 MB
  float* s_rel = (float*)(w + off); off += 128;

  if (ws_size < off){
    k_sentinel<<<(NND + 255)/256, 256, 0, stream>>>(out, (float)ws_size * 1e-6f);
    return;
  }

  // one-time CSR build (layer-invariant)
  k_init <<<(NND + 255)/256, 256, 0, stream>>>(node, B, count);
  k_hist <<<4096, 256, 0, stream>>>(dst, count);
  k_scan <<<1, 1024, 0, stream>>>(count, row_ptr, cursor);
  k_build<<<4096, 256, 0, stream>>>(src, dst, et, cursor, cse);

  for (int l = 0; l < NLAYERS; l++){
    const float* W_l   = W   + l*DIM*DIM;
    const float* Wr_l  = Wr  + l*DIM*DIM;
    const float* a_l   = a   + l*3*DIM;
    const float* rel_l = rel + l*NREL*DIM;
    bf16* xcur  = (l == 0) ? B : XN;   // transformed in-place to xt
    bf16* xnext = (l == 0) ? XN : B;
    k_rel <<<1, 64, 0, stream>>>(Wr_l, a_l, rel_l, s_rel);
    k_gemm<<<2048, 256, 0, stream>>>(xcur, xcur, W_l, a_l, s_src, s_dst);
    k_agg <<<2048, 256, 0, stream>>>(row_ptr, cse, s_src, s_dst, s_rel, xcur, xnext, out, l);
  }
  k_final<<<(NND + 255)/256, 256, 0, stream>>>(node, out);
}

// Round 6
// 768.161 us; speedup vs baseline: 3.5218x; 1.3433x over previous
//
#include <hip/hip_runtime.h>
#include <hip/hip_bf16.h>
#include <cmath>

#define NODES 150000
#define DIM 64
#define EDGES 1200000
#define NREL 32
#define NLAYERS 2
#define NND (NODES*DIM)
#define SCAN_NB ((NODES + 255)/256)   // 586

typedef __hip_bfloat16 bf16;

__device__ __forceinline__ float b2f(bf16 v){ return __bfloat162float(v); }

// sentinel: encode ws_size (MB) into output (tripwire only)
__global__ void __launch_bounds__(256) k_sentinel(float* __restrict__ out, float wsmb){
  int i = blockIdx.x*256 + threadIdx.x;
  if (i < NND) out[i] = wsmb;
}

// node f32 -> bf16 working buffer; zero count[]
__global__ void __launch_bounds__(256) k_init(const float* __restrict__ node, bf16* __restrict__ x,
                                              int* __restrict__ count){
  int i = blockIdx.x*256 + threadIdx.x;
  if (i < NND) x[i] = __float2bfloat16(node[i]);
  if (i < NODES) count[i] = 0;
}

// one-time: histogram count[dst]++
__global__ void __launch_bounds__(256) k_hist(const int* __restrict__ dst, int* __restrict__ count){
  int tid0 = blockIdx.x*256 + threadIdx.x;
  int stride = gridDim.x*256;
  for (int e = tid0; e < EDGES; e += stride)
    atomicAdd(&count[dst[e]], 1);
}

// scan phase 1: per-block (256 nodes) exclusive scan + block sum
__global__ void __launch_bounds__(256) k_scan1(const int* __restrict__ count,
                                               int* __restrict__ lscan,
                                               int* __restrict__ bsum){
  int tid = threadIdx.x;
  int i = blockIdx.x*256 + tid;
  int c = (i < NODES) ? count[i] : 0;
  __shared__ int s[256];
  s[tid] = c;
  __syncthreads();
  #pragma unroll
  for (int off = 1; off < 256; off <<= 1){
    int t = (tid >= off) ? s[tid - off] : 0;
    __syncthreads();
    s[tid] += t;
    __syncthreads();
  }
  if (i < NODES) lscan[i] = s[tid] - c;
  if (tid == 255) bsum[blockIdx.x] = s[255];
}

// scan phase 2: single block scans the SCAN_NB block sums (exclusive, in place)
__global__ void __launch_bounds__(1024) k_scan2(int* __restrict__ bsum){
  int tid = threadIdx.x;
  int c = (tid < SCAN_NB) ? bsum[tid] : 0;
  __shared__ int s[1024];
  s[tid] = c;
  __syncthreads();
  #pragma unroll
  for (int off = 1; off < 1024; off <<= 1){
    int t = (tid >= off) ? s[tid - off] : 0;
    __syncthreads();
    s[tid] += t;
    __syncthreads();
  }
  if (tid < SCAN_NB) bsum[tid] = s[tid] - c;
}

// scan phase 3: row_ptr = lscan + bsum[block]; cursor copy; cap entry
__global__ void __launch_bounds__(256) k_scan3(const int* __restrict__ lscan,
                                               const int* __restrict__ bsum,
                                               int* __restrict__ row_ptr,
                                               int* __restrict__ cursor){
  int i = blockIdx.x*256 + threadIdx.x;
  if (i < NODES){
    int v = lscan[i] + bsum[i >> 8];
    row_ptr[i] = v;
    cursor[i]  = v;
  }
  if (i == NODES) row_ptr[NODES] = EDGES;
}

// one-time: scatter packed (src | et<<18) into CSR slots
__global__ void __launch_bounds__(256) k_build(const int* __restrict__ src, const int* __restrict__ dst,
                                               const int* __restrict__ et,
                                               int* __restrict__ cursor,
                                               unsigned* __restrict__ cse){
  int tid0 = blockIdx.x*256 + threadIdx.x;
  int stride = gridDim.x*256;
  for (int e = tid0; e < EDGES; e += stride){
    int p = atomicAdd(&cursor[dst[e]], 1);
    cse[p] = (unsigned)src[e] | ((unsigned)et[e] << 18);
  }
}

// per layer: s_rel[r] = rel[r] . (W_r @ a_rel)
__global__ void k_rel(const float* __restrict__ Wr_l, const float* __restrict__ a_l,
                      const float* __restrict__ rel_l, float* __restrict__ s_rel){
  __shared__ float w[DIM];
  int t = threadIdx.x; // 64 threads
  float s = 0.f;
  for (int j = 0; j < DIM; j++) s += Wr_l[t*DIM + j] * a_l[DIM + j];
  w[t] = s;
  __syncthreads();
  if (t < NREL){
    float r = 0.f;
    for (int k = 0; k < DIM; k++) r += rel_l[t*DIM + k] * w[k];
    s_rel[t] = r;
  }
}

// per layer: xt = x @ W (bf16->bf16, in-place safe; row private to one wave)
// s_src = xt . a[0:64], s_dst = xt . a[128:192]
__global__ void __launch_bounds__(256) k_gemm(const bf16* xin, bf16* xt,
                                              const float* __restrict__ W_l,
                                              const float* __restrict__ a_l,
                                              float* __restrict__ s_src_a,
                                              float* __restrict__ s_dst_a){
  __shared__ float Ws[DIM*DIM];
  int tid = threadIdx.x;
  for (int i = tid; i < DIM*DIM; i += 256) Ws[i] = W_l[i];
  __syncthreads();
  int lane = tid & 63;
  int wid  = tid >> 6;
  float asrc = a_l[lane];
  float adst = a_l[2*DIM + lane];
  int gw = blockIdx.x*4 + wid;
  int nw = gridDim.x*4;
  for (int row = gw; row < NODES; row += nw){
    float xv = b2f(xin[row*DIM + lane]);
    float accv = 0.f;
    #pragma unroll
    for (int k = 0; k < DIM; k++)
      accv = fmaf(__shfl(xv, k, 64), Ws[k*DIM + lane], accv);
    xt[row*DIM + lane] = __float2bfloat16(accv);
    float p = accv * asrc, q = accv * adst;
    #pragma unroll
    for (int off = 32; off > 0; off >>= 1){
      p += __shfl_xor(p, off, 64);
      q += __shfl_xor(q, off, 64);
    }
    if (lane == 0){ s_src_a[row] = p; s_dst_a[row] = q; }
  }
}

// per layer, one wave per dst row: scores inline (max-shift dropped — softmax
// exactly invariant), h = sum(w*xt[src])/(sum w + 1e-10); ELU; L2-norm;
// write x_next (bf16); acc into d_out (f32): mode0 store, mode1 add.
__global__ void __launch_bounds__(256) k_agg(const int* __restrict__ row_ptr,
                                             const unsigned* __restrict__ cse,
                                             const float* __restrict__ s_src_a,
                                             const float* __restrict__ s_dst_a,
                                             const float* __restrict__ s_rel,
                                             const bf16* __restrict__ xt,
                                             bf16* __restrict__ xnext,
                                             float* __restrict__ outacc, int mode){
  int lane = threadIdx.x & 63;
  int gw = blockIdx.x*4 + (threadIdx.x >> 6);
  int nw = gridDim.x*4;
  for (int row = gw; row < NODES; row += nw){
    int beg = row_ptr[row], end = row_ptr[row+1];
    float sdst = s_dst_a[row];
    float hacc = 0.f, wsum = 0.f;
    for (int j = beg; j < end; j++){
      unsigned pk = cse[j];                 // wave-uniform 4B broadcast
      int s = (int)(pk & 0x3FFFFu);
      int r = (int)(pk >> 18);
      float e = s_src_a[s] + s_rel[r] + sdst;  // uniform scalar loads
      e = e > 0.f ? e : 0.2f*e;
      float wgt = __expf(e);
      float xv = b2f(xt[(size_t)s*DIM + lane]);  // coalesced 128B row gather
      hacc = fmaf(wgt, xv, hacc);
      wsum += wgt;
    }
    float v = hacc / (wsum + 1e-10f);
    v = v > 0.f ? v : expm1f(v);
    float ss = v*v;
    #pragma unroll
    for (int off = 32; off > 0; off >>= 1) ss += __shfl_xor(ss, off, 64);
    float n = fmaxf(sqrtf(ss), 1e-12f);
    float x = v / n;
    int i = row*DIM + lane;
    xnext[i] = __float2bfloat16(x);
    if (mode == 0) outacc[i] = x;
    else           outacc[i] += x;
  }
}

// out = (node_emb + acc) / 3   (f32)
__global__ void __launch_bounds__(256) k_final(const float* __restrict__ node, float* outacc){
  int i = blockIdx.x*256 + threadIdx.x;
  if (i < NND) outacc[i] = (node[i] + outacc[i]) * (1.f/3.f);
}

extern "C" void kernel_launch(void* const* d_in, const int* in_sizes, int n_in,
                              void* d_out, int out_size, void* d_ws, size_t ws_size,
                              hipStream_t stream){
  const float* node = (const float*)d_in[0];
  const float* W    = (const float*)d_in[1];
  const float* Wr   = (const float*)d_in[2];
  const float* a    = (const float*)d_in[3];
  const float* rel  = (const float*)d_in[4];
  const int*   ei   = (const int*)d_in[5];
  const int*   et   = (const int*)d_in[6];
  const int* src = ei;
  const int* dst = ei + EDGES;
  float* out = (float*)d_out;

  // ---- workspace layout (~47 MB; round 4 proved >= 53.4 MB available) ----
  char* w = (char*)d_ws;
  size_t off = 0;
  bf16* B  = (bf16*)(w + off); off += (size_t)NND*2;             // 19.2 MB x/xt ping
  bf16* XN = (bf16*)(w + off); off += (size_t)NND*2;             // 19.2 MB x pong
  unsigned* cse = (unsigned*)(w + off); off += (size_t)EDGES*4;  //  4.8 MB CSR packed (src|et<<18)
  int* row_ptr = (int*)(w + off); off += (size_t)(NODES+1)*4;    //  0.6 MB
  int* cursor  = (int*)(w + off); off += (size_t)NODES*4;        //  0.6 MB
  int* count   = (int*)(w + off); off += (size_t)NODES*4;        //  0.6 MB
  int* lscan   = (int*)(w + off); off += (size_t)NODES*4;        //  0.6 MB
  int* bsum    = (int*)(w + off); off += (size_t)SCAN_NB*4;      //  2.3 KB
  float* s_src = (float*)(w + off); off += (size_t)NODES*4;      //  0.6 MB
  float* s_dst = (float*)(w + off); off += (size_t)NODES*4;      //  0.6 MB
  float* s_rel = (float*)(w + off); off += 128;

  if (ws_size < off){
    k_sentinel<<<(NND + 255)/256, 256, 0, stream>>>(out, (float)ws_size * 1e-6f);
    return;
  }

  // one-time CSR build (layer-invariant)
  k_init <<<(NND + 255)/256, 256, 0, stream>>>(node, B, count);
  k_hist <<<4096, 256, 0, stream>>>(dst, count);
  k_scan1<<<SCAN_NB, 256, 0, stream>>>(count, lscan, bsum);
  k_scan2<<<1, 1024, 0, stream>>>(bsum);
  k_scan3<<<SCAN_NB + 1, 256, 0, stream>>>(lscan, bsum, row_ptr, cursor);
  k_build<<<4096, 256, 0, stream>>>(src, dst, et, cursor, cse);

  for (int l = 0; l < NLAYERS; l++){
    const float* W_l   = W   + l*DIM*DIM;
    const float* Wr_l  = Wr  + l*DIM*DIM;
    const float* a_l   = a   + l*3*DIM;
    const float* rel_l = rel + l*NREL*DIM;
    bf16* xcur  = (l == 0) ? B : XN;   // transformed in-place to xt
    bf16* xnext = (l == 0) ? XN : B;
    k_rel <<<1, 64, 0, stream>>>(Wr_l, a_l, rel_l, s_rel);
    k_gemm<<<2048, 256, 0, stream>>>(xcur, xcur, W_l, a_l, s_src, s_dst);
    k_agg <<<2048, 256, 0, stream>>>(row_ptr, cse, s_src, s_dst, s_rel, xcur, xnext, out, l);
  }
  k_final<<<(NND + 255)/256, 256, 0, stream>>>(node, out);
}

// Round 7
// 554.094 us; speedup vs baseline: 4.8824x; 1.3863x over previous
//
#include <hip/hip_runtime.h>
#include <hip/hip_bf16.h>
#include <cmath>

#define NODES 150000
#define DIM 64
#define EDGES 1200000
#define NREL 32
#define NLAYERS 2
#define NND (NODES*DIM)
#define SCAN_NB ((NODES + 255)/256)   // 586
#define RBLK (NODES/16)               // 9375 row-blocks of 16

typedef __hip_bfloat16 bf16;
typedef __attribute__((ext_vector_type(8))) short bf16x8;  // MFMA A/B frag (4 VGPRs)
typedef __attribute__((ext_vector_type(4))) float f32x4;   // MFMA C/D frag

__device__ __forceinline__ float b2f(bf16 v){ return __bfloat162float(v); }
__device__ __forceinline__ short f2bs(float f){
  bf16 h = __float2bfloat16(f);
  return *(short*)&h;
}

// sentinel: encode ws_size (MB) into output (tripwire only)
__global__ void __launch_bounds__(256) k_sentinel(float* __restrict__ out, float wsmb){
  int i = blockIdx.x*256 + threadIdx.x;
  if (i < NND) out[i] = wsmb;
}

// node f32 -> bf16 working buffer; zero count[]
__global__ void __launch_bounds__(256) k_init(const float* __restrict__ node, bf16* __restrict__ x,
                                              int* __restrict__ count){
  int i = blockIdx.x*256 + threadIdx.x;
  if (i < NND) x[i] = __float2bfloat16(node[i]);
  if (i < NODES) count[i] = 0;
}

// one-time: histogram count[dst]++
__global__ void __launch_bounds__(256) k_hist(const int* __restrict__ dst, int* __restrict__ count){
  int tid0 = blockIdx.x*256 + threadIdx.x;
  int stride = gridDim.x*256;
  for (int e = tid0; e < EDGES; e += stride)
    atomicAdd(&count[dst[e]], 1);
}

// scan phase 1: per-block (256 nodes) exclusive scan + block sum
__global__ void __launch_bounds__(256) k_scan1(const int* __restrict__ count,
                                               int* __restrict__ lscan,
                                               int* __restrict__ bsum){
  int tid = threadIdx.x;
  int i = blockIdx.x*256 + tid;
  int c = (i < NODES) ? count[i] : 0;
  __shared__ int s[256];
  s[tid] = c;
  __syncthreads();
  #pragma unroll
  for (int off = 1; off < 256; off <<= 1){
    int t = (tid >= off) ? s[tid - off] : 0;
    __syncthreads();
    s[tid] += t;
    __syncthreads();
  }
  if (i < NODES) lscan[i] = s[tid] - c;
  if (tid == 255) bsum[blockIdx.x] = s[255];
}

// scan phase 2: single block scans the SCAN_NB block sums (exclusive, in place)
__global__ void __launch_bounds__(1024) k_scan2(int* __restrict__ bsum){
  int tid = threadIdx.x;
  int c = (tid < SCAN_NB) ? bsum[tid] : 0;
  __shared__ int s[1024];
  s[tid] = c;
  __syncthreads();
  #pragma unroll
  for (int off = 1; off < 1024; off <<= 1){
    int t = (tid >= off) ? s[tid - off] : 0;
    __syncthreads();
    s[tid] += t;
    __syncthreads();
  }
  if (tid < SCAN_NB) bsum[tid] = s[tid] - c;
}

// scan phase 3: row_ptr = lscan + bsum[block]; cursor copy; cap entry
__global__ void __launch_bounds__(256) k_scan3(const int* __restrict__ lscan,
                                               const int* __restrict__ bsum,
                                               int* __restrict__ row_ptr,
                                               int* __restrict__ cursor){
  int i = blockIdx.x*256 + threadIdx.x;
  if (i < NODES){
    int v = lscan[i] + bsum[i >> 8];
    row_ptr[i] = v;
    cursor[i]  = v;
  }
  if (i == NODES) row_ptr[NODES] = EDGES;
}

// one-time: scatter packed (src | et<<18) into CSR slots
__global__ void __launch_bounds__(256) k_build(const int* __restrict__ src, const int* __restrict__ dst,
                                               const int* __restrict__ et,
                                               int* __restrict__ cursor,
                                               unsigned* __restrict__ cse){
  int tid0 = blockIdx.x*256 + threadIdx.x;
  int stride = gridDim.x*256;
  for (int e = tid0; e < EDGES; e += stride){
    int p = atomicAdd(&cursor[dst[e]], 1);
    cse[p] = (unsigned)src[e] | ((unsigned)et[e] << 18);
  }
}

// per layer: s_rel[r] = rel[r] . (W_r @ a_rel)
__global__ void k_rel(const float* __restrict__ Wr_l, const float* __restrict__ a_l,
                      const float* __restrict__ rel_l, float* __restrict__ s_rel){
  __shared__ float w[DIM];
  int t = threadIdx.x; // 64 threads
  float s = 0.f;
  for (int j = 0; j < DIM; j++) s += Wr_l[t*DIM + j] * a_l[DIM + j];
  w[t] = s;
  __syncthreads();
  if (t < NREL){
    float r = 0.f;
    for (int k = 0; k < DIM; k++) r += rel_l[t*DIM + k] * w[k];
    s_rel[t] = r;
  }
}

// per layer, MFMA: xt = x @ W (bf16->bf16, in-place safe: 16-row tile private
// to one wave). Each wave: B-frags (W) built once, then per 16-row tile:
// 2 A-loads (16B each) + 8 mfma_f32_16x16x32_bf16 + bf16 stores.
// s_src/s_dst computed from accumulator registers.
// Layouts (HW-verified m89/m120): A[m=lane&15][k=(lane>>4)*8+j],
// B[k=(lane>>4)*8+j][n=lane&15], C/D: col=lane&15, row=(lane>>4)*4+reg.
__global__ void __launch_bounds__(256) k_gemm(const bf16* xin, bf16* xt,
                                              const float* __restrict__ W_l,
                                              const float* __restrict__ a_l,
                                              float* __restrict__ s_src_a,
                                              float* __restrict__ s_dst_a){
  __shared__ float Ws[DIM*DIM];   // 16 KB staged f32 W
  int tid = threadIdx.x;
  for (int i = tid; i < DIM*DIM; i += 256) Ws[i] = W_l[i];
  __syncthreads();

  int lane = tid & 63;
  int l15  = lane & 15;
  int quad = lane >> 4;

  // B fragments: bfrag[nt][kh] holds B[k][n], n = nt*16+l15, k = kh*32+quad*8+j
  bf16x8 bfrag[4][2];
  #pragma unroll
  for (int nt = 0; nt < 4; nt++)
    #pragma unroll
    for (int kh = 0; kh < 2; kh++)
      #pragma unroll
      for (int j = 0; j < 8; j++){
        int k = kh*32 + quad*8 + j;
        ((short*)&bfrag[nt][kh])[j] = f2bs(Ws[k*DIM + nt*16 + l15]);
      }

  // a-vector cols for this lane: col = nt*16 + l15
  float asrc[4], adst[4];
  #pragma unroll
  for (int nt = 0; nt < 4; nt++){
    asrc[nt] = a_l[nt*16 + l15];
    adst[nt] = a_l[2*DIM + nt*16 + l15];
  }

  int gw = blockIdx.x*4 + (tid >> 6);
  int nw = gridDim.x*4;
  for (int rb = gw; rb < RBLK; rb += nw){
    int r0 = rb*16;
    // A fragments: row = r0+l15, k = kh*32 + quad*8 + j (8 consecutive bf16 = 16B)
    const size_t abase = (size_t)(r0 + l15)*DIM + quad*8;
    bf16x8 a0 = *(const bf16x8*)(xin + abase);
    bf16x8 a1 = *(const bf16x8*)(xin + abase + 32);

    f32x4 acc[4];
    #pragma unroll
    for (int nt = 0; nt < 4; nt++){
      acc[nt] = (f32x4){0.f, 0.f, 0.f, 0.f};
      acc[nt] = __builtin_amdgcn_mfma_f32_16x16x32_bf16(a0, bfrag[nt][0], acc[nt], 0, 0, 0);
      acc[nt] = __builtin_amdgcn_mfma_f32_16x16x32_bf16(a1, bfrag[nt][1], acc[nt], 0, 0, 0);
    }

    // s_src / s_dst: row r0+quad*4+i ; per-lane partial over its 4 cols, then
    // xor-reduce across the 16 lanes of the quad (masks 1,2,4,8 stay in-group)
    float p[4], q[4];
    #pragma unroll
    for (int i = 0; i < 4; i++){
      p[i] = acc[0][i]*asrc[0] + acc[1][i]*asrc[1] + acc[2][i]*asrc[2] + acc[3][i]*asrc[3];
      q[i] = acc[0][i]*adst[0] + acc[1][i]*adst[1] + acc[2][i]*adst[2] + acc[3][i]*adst[3];
      #pragma unroll
      for (int off = 8; off > 0; off >>= 1){
        p[i] += __shfl_xor(p[i], off, 64);
        q[i] += __shfl_xor(q[i], off, 64);
      }
    }
    if (l15 < 4){
      float pv = (l15 == 0) ? p[0] : (l15 == 1) ? p[1] : (l15 == 2) ? p[2] : p[3];
      float qv = (l15 == 0) ? q[0] : (l15 == 1) ? q[1] : (l15 == 2) ? q[2] : q[3];
      int r = r0 + quad*4 + l15;
      s_src_a[r] = pv;
      s_dst_a[r] = qv;
    }

    // store xt tile (bf16): row = r0+quad*4+i, col = nt*16+l15
    #pragma unroll
    for (int nt = 0; nt < 4; nt++)
      #pragma unroll
      for (int i = 0; i < 4; i++)
        xt[(size_t)(r0 + quad*4 + i)*DIM + nt*16 + l15] = __float2bfloat16(acc[nt][i]);
  }
}

// per layer, one wave per dst row: scores inline (max-shift dropped — softmax
// exactly invariant), h = sum(w*xt[src])/(sum w + 1e-10); ELU; L2-norm;
// write x_next (bf16); acc into d_out (f32): mode0 store, mode1 add.
__global__ void __launch_bounds__(256) k_agg(const int* __restrict__ row_ptr,
                                             const unsigned* __restrict__ cse,
                                             const float* __restrict__ s_src_a,
                                             const float* __restrict__ s_dst_a,
                                             const float* __restrict__ s_rel,
                                             const bf16* __restrict__ xt,
                                             bf16* __restrict__ xnext,
                                             float* __restrict__ outacc, int mode){
  int lane = threadIdx.x & 63;
  int gw = blockIdx.x*4 + (threadIdx.x >> 6);
  int nw = gridDim.x*4;
  for (int row = gw; row < NODES; row += nw){
    int beg = row_ptr[row], end = row_ptr[row+1];
    float sdst = s_dst_a[row];
    float hacc = 0.f, wsum = 0.f;
    for (int j = beg; j < end; j++){
      unsigned pk = cse[j];                 // wave-uniform 4B broadcast
      int s = (int)(pk & 0x3FFFFu);
      int r = (int)(pk >> 18);
      float e = s_src_a[s] + s_rel[r] + sdst;  // uniform scalar loads
      e = e > 0.f ? e : 0.2f*e;
      float wgt = __expf(e);
      float xv = b2f(xt[(size_t)s*DIM + lane]);  // coalesced 128B row gather
      hacc = fmaf(wgt, xv, hacc);
      wsum += wgt;
    }
    float v = hacc / (wsum + 1e-10f);
    v = v > 0.f ? v : expm1f(v);
    float ss = v*v;
    #pragma unroll
    for (int off = 32; off > 0; off >>= 1) ss += __shfl_xor(ss, off, 64);
    float n = fmaxf(sqrtf(ss), 1e-12f);
    float x = v / n;
    int i = row*DIM + lane;
    xnext[i] = __float2bfloat16(x);
    if (mode == 0) outacc[i] = x;
    else           outacc[i] += x;
  }
}

// out = (node_emb + acc) / 3   (f32)
__global__ void __launch_bounds__(256) k_final(const float* __restrict__ node, float* outacc){
  int i = blockIdx.x*256 + threadIdx.x;
  if (i < NND) outacc[i] = (node[i] + outacc[i]) * (1.f/3.f);
}

extern "C" void kernel_launch(void* const* d_in, const int* in_sizes, int n_in,
                              void* d_out, int out_size, void* d_ws, size_t ws_size,
                              hipStream_t stream){
  const float* node = (const float*)d_in[0];
  const float* W    = (const float*)d_in[1];
  const float* Wr   = (const float*)d_in[2];
  const float* a    = (const float*)d_in[3];
  const float* rel  = (const float*)d_in[4];
  const int*   ei   = (const int*)d_in[5];
  const int*   et   = (const int*)d_in[6];
  const int* src = ei;
  const int* dst = ei + EDGES;
  float* out = (float*)d_out;

  // ---- workspace layout (~47 MB; proven to fit) ----
  char* w = (char*)d_ws;
  size_t off = 0;
  bf16* B  = (bf16*)(w + off); off += (size_t)NND*2;             // 19.2 MB x/xt ping
  bf16* XN = (bf16*)(w + off); off += (size_t)NND*2;             // 19.2 MB x pong
  unsigned* cse = (unsigned*)(w + off); off += (size_t)EDGES*4;  //  4.8 MB CSR packed (src|et<<18)
  int* row_ptr = (int*)(w + off); off += (size_t)(NODES+1)*4;    //  0.6 MB
  int* cursor  = (int*)(w + off); off += (size_t)NODES*4;        //  0.6 MB
  int* count   = (int*)(w + off); off += (size_t)NODES*4;        //  0.6 MB
  int* lscan   = (int*)(w + off); off += (size_t)NODES*4;        //  0.6 MB
  int* bsum    = (int*)(w + off); off += (size_t)SCAN_NB*4;      //  2.3 KB
  float* s_src = (float*)(w + off); off += (size_t)NODES*4;      //  0.6 MB
  float* s_dst = (float*)(w + off); off += (size_t)NODES*4;      //  0.6 MB
  float* s_rel = (float*)(w + off); off += 128;

  if (ws_size < off){
    k_sentinel<<<(NND + 255)/256, 256, 0, stream>>>(out, (float)ws_size * 1e-6f);
    return;
  }

  // one-time CSR build (layer-invariant)
  k_init <<<(NND + 255)/256, 256, 0, stream>>>(node, B, count);
  k_hist <<<4096, 256, 0, stream>>>(dst, count);
  k_scan1<<<SCAN_NB, 256, 0, stream>>>(count, lscan, bsum);
  k_scan2<<<1, 1024, 0, stream>>>(bsum);
  k_scan3<<<SCAN_NB + 1, 256, 0, stream>>>(lscan, bsum, row_ptr, cursor);
  k_build<<<4096, 256, 0, stream>>>(src, dst, et, cursor, cse);

  for (int l = 0; l < NLAYERS; l++){
    const float* W_l   = W   + l*DIM*DIM;
    const float* Wr_l  = Wr  + l*DIM*DIM;
    const float* a_l   = a   + l*3*DIM;
    const float* rel_l = rel + l*NREL*DIM;
    bf16* xcur  = (l == 0) ? B : XN;   // transformed in-place to xt
    bf16* xnext = (l == 0) ? XN : B;
    k_rel <<<1, 64, 0, stream>>>(Wr_l, a_l, rel_l, s_rel);
    k_gemm<<<1024, 256, 0, stream>>>(xcur, xcur, W_l, a_l, s_src, s_dst);
    k_agg <<<2048, 256, 0, stream>>>(row_ptr, cse, s_src, s_dst, s_rel, xcur, xnext, out, l);
  }
  k_final<<<(NND + 255)/256, 256, 0, stream>>>(node, out);
}

// Round 8
// 476.755 us; speedup vs baseline: 5.6744x; 1.1622x over previous
//
#include <hip/hip_runtime.h>
#include <hip/hip_bf16.h>
#include <cmath>

#define NODES 150000
#define DIM 64
#define EDGES 1200000
#define NREL 32
#define NLAYERS 2
#define NND (NODES*DIM)
#define SCAN_NB ((NODES + 255)/256)   // 586
#define RBLK (NODES/16)               // 9375 row-blocks of 16

typedef __hip_bfloat16 bf16;
typedef __attribute__((ext_vector_type(8))) short bf16x8;  // MFMA A/B frag (4 VGPRs)
typedef __attribute__((ext_vector_type(4))) float f32x4;   // MFMA C/D frag

__device__ __forceinline__ float b2f(bf16 v){ return __bfloat162float(v); }
__device__ __forceinline__ short f2bs(float f){
  bf16 h = __float2bfloat16(f);
  return *(short*)&h;
}

// sentinel: encode ws_size (MB) into output (tripwire only)
__global__ void __launch_bounds__(256) k_sentinel(float* __restrict__ out, float wsmb){
  int i = blockIdx.x*256 + threadIdx.x;
  if (i < NND) out[i] = wsmb;
}

// node f32 -> bf16 working buffer; zero count[]
__global__ void __launch_bounds__(256) k_init(const float* __restrict__ node, bf16* __restrict__ x,
                                              int* __restrict__ count){
  int i = blockIdx.x*256 + threadIdx.x;
  if (i < NND) x[i] = __float2bfloat16(node[i]);
  if (i < NODES) count[i] = 0;
}

// one-time: histogram count[dst]++
__global__ void __launch_bounds__(256) k_hist(const int* __restrict__ dst, int* __restrict__ count){
  int tid0 = blockIdx.x*256 + threadIdx.x;
  int stride = gridDim.x*256;
  for (int e = tid0; e < EDGES; e += stride)
    atomicAdd(&count[dst[e]], 1);
}

// scan phase 1: per-block (256 nodes) exclusive scan + block sum
__global__ void __launch_bounds__(256) k_scan1(const int* __restrict__ count,
                                               int* __restrict__ lscan,
                                               int* __restrict__ bsum){
  int tid = threadIdx.x;
  int i = blockIdx.x*256 + tid;
  int c = (i < NODES) ? count[i] : 0;
  __shared__ int s[256];
  s[tid] = c;
  __syncthreads();
  #pragma unroll
  for (int off = 1; off < 256; off <<= 1){
    int t = (tid >= off) ? s[tid - off] : 0;
    __syncthreads();
    s[tid] += t;
    __syncthreads();
  }
  if (i < NODES) lscan[i] = s[tid] - c;
  if (tid == 255) bsum[blockIdx.x] = s[255];
}

// scan phase 2: single block scans the SCAN_NB block sums (exclusive, in place)
__global__ void __launch_bounds__(1024) k_scan2(int* __restrict__ bsum){
  int tid = threadIdx.x;
  int c = (tid < SCAN_NB) ? bsum[tid] : 0;
  __shared__ int s[1024];
  s[tid] = c;
  __syncthreads();
  #pragma unroll
  for (int off = 1; off < 1024; off <<= 1){
    int t = (tid >= off) ? s[tid - off] : 0;
    __syncthreads();
    s[tid] += t;
    __syncthreads();
  }
  if (tid < SCAN_NB) bsum[tid] = s[tid] - c;
}

// scan phase 3: row_ptr = lscan + bsum[block]; cursor copy; cap entry
__global__ void __launch_bounds__(256) k_scan3(const int* __restrict__ lscan,
                                               const int* __restrict__ bsum,
                                               int* __restrict__ row_ptr,
                                               int* __restrict__ cursor){
  int i = blockIdx.x*256 + threadIdx.x;
  if (i < NODES){
    int v = lscan[i] + bsum[i >> 8];
    row_ptr[i] = v;
    cursor[i]  = v;
  }
  if (i == NODES) row_ptr[NODES] = EDGES;
}

// one-time: scatter packed (src | et<<18) into CSR slots
__global__ void __launch_bounds__(256) k_build(const int* __restrict__ src, const int* __restrict__ dst,
                                               const int* __restrict__ et,
                                               int* __restrict__ cursor,
                                               unsigned* __restrict__ cse){
  int tid0 = blockIdx.x*256 + threadIdx.x;
  int stride = gridDim.x*256;
  for (int e = tid0; e < EDGES; e += stride){
    int p = atomicAdd(&cursor[dst[e]], 1);
    cse[p] = (unsigned)src[e] | ((unsigned)et[e] << 18);
  }
}

// per layer: s_rel[r] = rel[r] . (W_r @ a_rel)
__global__ void k_rel(const float* __restrict__ Wr_l, const float* __restrict__ a_l,
                      const float* __restrict__ rel_l, float* __restrict__ s_rel){
  __shared__ float w[DIM];
  int t = threadIdx.x; // 64 threads
  float s = 0.f;
  for (int j = 0; j < DIM; j++) s += Wr_l[t*DIM + j] * a_l[DIM + j];
  w[t] = s;
  __syncthreads();
  if (t < NREL){
    float r = 0.f;
    for (int k = 0; k < DIM; k++) r += rel_l[t*DIM + k] * w[k];
    s_rel[t] = r;
  }
}

// per layer, MFMA: xt = x @ W (bf16->bf16; in-place safe when xin==xt since the
// 16-row tile is wave-private). s_src/s_dst from accumulator registers.
// Layouts (HW-verified m89/m120): A[m=lane&15][k=(lane>>4)*8+j],
// B[k=(lane>>4)*8+j][n=lane&15], C/D: col=lane&15, row=(lane>>4)*4+reg.
__global__ void __launch_bounds__(256) k_gemm(const bf16* xin, bf16* xt,
                                              const float* __restrict__ W_l,
                                              const float* __restrict__ a_l,
                                              float* __restrict__ s_src_a,
                                              float* __restrict__ s_dst_a){
  __shared__ float Ws[DIM*DIM];   // 16 KB staged f32 W
  int tid = threadIdx.x;
  for (int i = tid; i < DIM*DIM; i += 256) Ws[i] = W_l[i];
  __syncthreads();

  int lane = tid & 63;
  int l15  = lane & 15;
  int quad = lane >> 4;

  bf16x8 bfrag[4][2];
  #pragma unroll
  for (int nt = 0; nt < 4; nt++)
    #pragma unroll
    for (int kh = 0; kh < 2; kh++)
      #pragma unroll
      for (int j = 0; j < 8; j++){
        int k = kh*32 + quad*8 + j;
        ((short*)&bfrag[nt][kh])[j] = f2bs(Ws[k*DIM + nt*16 + l15]);
      }

  float asrc[4], adst[4];
  #pragma unroll
  for (int nt = 0; nt < 4; nt++){
    asrc[nt] = a_l[nt*16 + l15];
    adst[nt] = a_l[2*DIM + nt*16 + l15];
  }

  int gw = blockIdx.x*4 + (tid >> 6);
  int nw = gridDim.x*4;
  for (int rb = gw; rb < RBLK; rb += nw){
    int r0 = rb*16;
    const size_t abase = (size_t)(r0 + l15)*DIM + quad*8;
    bf16x8 a0 = *(const bf16x8*)(xin + abase);
    bf16x8 a1 = *(const bf16x8*)(xin + abase + 32);

    f32x4 acc[4];
    #pragma unroll
    for (int nt = 0; nt < 4; nt++){
      acc[nt] = (f32x4){0.f, 0.f, 0.f, 0.f};
      acc[nt] = __builtin_amdgcn_mfma_f32_16x16x32_bf16(a0, bfrag[nt][0], acc[nt], 0, 0, 0);
      acc[nt] = __builtin_amdgcn_mfma_f32_16x16x32_bf16(a1, bfrag[nt][1], acc[nt], 0, 0, 0);
    }

    float p[4], q[4];
    #pragma unroll
    for (int i = 0; i < 4; i++){
      p[i] = acc[0][i]*asrc[0] + acc[1][i]*asrc[1] + acc[2][i]*asrc[2] + acc[3][i]*asrc[3];
      q[i] = acc[0][i]*adst[0] + acc[1][i]*adst[1] + acc[2][i]*adst[2] + acc[3][i]*adst[3];
      #pragma unroll
      for (int off = 8; off > 0; off >>= 1){
        p[i] += __shfl_xor(p[i], off, 64);
        q[i] += __shfl_xor(q[i], off, 64);
      }
    }
    if (l15 < 4){
      float pv = (l15 == 0) ? p[0] : (l15 == 1) ? p[1] : (l15 == 2) ? p[2] : p[3];
      float qv = (l15 == 0) ? q[0] : (l15 == 1) ? q[1] : (l15 == 2) ? q[2] : q[3];
      int r = r0 + quad*4 + l15;
      s_src_a[r] = pv;
      s_dst_a[r] = qv;
    }

    #pragma unroll
    for (int nt = 0; nt < 4; nt++)
      #pragma unroll
      for (int i = 0; i < 4; i++)
        xt[(size_t)(r0 + quad*4 + i)*DIM + nt*16 + l15] = __float2bfloat16(acc[nt][i]);
  }
}

// per layer, one wave per dst row. Lane-parallel scoring: lane j computes the
// weight of edge beg+j (coalesced cse load, one expf for 64 edges); gather
// loop is then shfl->gather->fma with independent loads (deep vmcnt pipeline).
// mode0: write xnext only. mode1: fused finale out=(node+x1+x2)/3, no xnext.
__global__ void __launch_bounds__(256) k_agg(const int* __restrict__ row_ptr,
                                             const unsigned* __restrict__ cse,
                                             const float* __restrict__ s_src_a,
                                             const float* __restrict__ s_dst_a,
                                             const float* __restrict__ s_rel,
                                             const bf16* __restrict__ xt,
                                             bf16* __restrict__ xnext,
                                             const float* __restrict__ node,
                                             const bf16* __restrict__ x1,
                                             float* __restrict__ out, int mode){
  int lane = threadIdx.x & 63;
  int gw = blockIdx.x*4 + (threadIdx.x >> 6);
  int nw = gridDim.x*4;
  for (int row = gw; row < NODES; row += nw){
    int beg = row_ptr[row], end = row_ptr[row+1];
    float sdst = s_dst_a[row];
    float hacc = 0.f, wsuml = 0.f;
    for (int jb = beg; jb < end; jb += 64){
      int n = end - jb; if (n > 64) n = 64;
      // lane-parallel: this lane's edge
      unsigned pkv = 0u;
      float wl = 0.f;
      if (lane < n){
        pkv = cse[jb + lane];
        int sl = (int)(pkv & 0x3FFFFu);
        int rl = (int)(pkv >> 18);
        float e = s_src_a[sl] + s_rel[rl] + sdst;
        e = e > 0.f ? e : 0.2f*e;
        wl = __expf(e);
      }
      wsuml += wl;
      // gather loop: broadcast (s, w) via shfl, loads independent across j
      for (int j = 0; j < n; j++){
        int s      = (int)(__shfl(pkv, j, 64) & 0x3FFFFu);
        float wgt  = __shfl(wl, j, 64);
        float xv   = b2f(xt[(size_t)s*DIM + lane]);
        hacc = fmaf(wgt, xv, hacc);
      }
    }
    // full-wave reduce of wsum
    float wsum = wsuml;
    #pragma unroll
    for (int off = 32; off > 0; off >>= 1) wsum += __shfl_xor(wsum, off, 64);

    float v = hacc / (wsum + 1e-10f);
    v = v > 0.f ? v : expm1f(v);
    float ss = v*v;
    #pragma unroll
    for (int off = 32; off > 0; off >>= 1) ss += __shfl_xor(ss, off, 64);
    float nrm = fmaxf(sqrtf(ss), 1e-12f);
    float x = v / nrm;
    int i = row*DIM + lane;
    if (mode == 0){
      xnext[i] = __float2bfloat16(x);
    } else {
      out[i] = (node[i] + b2f(x1[i]) + x) * (1.f/3.f);
    }
  }
}

extern "C" void kernel_launch(void* const* d_in, const int* in_sizes, int n_in,
                              void* d_out, int out_size, void* d_ws, size_t ws_size,
                              hipStream_t stream){
  const float* node = (const float*)d_in[0];
  const float* W    = (const float*)d_in[1];
  const float* Wr   = (const float*)d_in[2];
  const float* a    = (const float*)d_in[3];
  const float* rel  = (const float*)d_in[4];
  const int*   ei   = (const int*)d_in[5];
  const int*   et   = (const int*)d_in[6];
  const int* src = ei;
  const int* dst = ei + EDGES;
  float* out = (float*)d_out;

  // ---- workspace layout (~47 MB; proven to fit) ----
  char* w = (char*)d_ws;
  size_t off = 0;
  bf16* B  = (bf16*)(w + off); off += (size_t)NND*2;             // 19.2 MB node16/xt1, then xt2
  bf16* XN = (bf16*)(w + off); off += (size_t)NND*2;             // 19.2 MB x1 (persists through layer 1)
  unsigned* cse = (unsigned*)(w + off); off += (size_t)EDGES*4;  //  4.8 MB CSR packed (src|et<<18)
  int* row_ptr = (int*)(w + off); off += (size_t)(NODES+1)*4;    //  0.6 MB
  int* cursor  = (int*)(w + off); off += (size_t)NODES*4;        //  0.6 MB
  int* count   = (int*)(w + off); off += (size_t)NODES*4;        //  0.6 MB
  int* lscan   = (int*)(w + off); off += (size_t)NODES*4;        //  0.6 MB
  int* bsum    = (int*)(w + off); off += (size_t)SCAN_NB*4;      //  2.3 KB
  float* s_src = (float*)(w + off); off += (size_t)NODES*4;      //  0.6 MB
  float* s_dst = (float*)(w + off); off += (size_t)NODES*4;      //  0.6 MB
  float* s_rel = (float*)(w + off); off += 128;

  if (ws_size < off){
    k_sentinel<<<(NND + 255)/256, 256, 0, stream>>>(out, (float)ws_size * 1e-6f);
    return;
  }

  // one-time CSR build (layer-invariant)
  k_init <<<(NND + 255)/256, 256, 0, stream>>>(node, B, count);
  k_hist <<<4096, 256, 0, stream>>>(dst, count);
  k_scan1<<<SCAN_NB, 256, 0, stream>>>(count, lscan, bsum);
  k_scan2<<<1, 1024, 0, stream>>>(bsum);
  k_scan3<<<SCAN_NB + 1, 256, 0, stream>>>(lscan, bsum, row_ptr, cursor);
  k_build<<<4096, 256, 0, stream>>>(src, dst, et, cursor, cse);

  // layer 0: B(node bf16) -> xt1 in-place in B; x1 -> XN
  k_rel <<<1, 64, 0, stream>>>(Wr, a, rel, s_rel);
  k_gemm<<<1024, 256, 0, stream>>>(B, B, W, a, s_src, s_dst);
  k_agg <<<2048, 256, 0, stream>>>(row_ptr, cse, s_src, s_dst, s_rel, B, XN,
                                   node, XN, out, 0);

  // layer 1: XN(x1) -> xt2 in B (keeps x1); fused finale writes out
  k_rel <<<1, 64, 0, stream>>>(Wr + DIM*DIM, a + 3*DIM, rel + NREL*DIM, s_rel);
  k_gemm<<<1024, 256, 0, stream>>>(XN, B, W + DIM*DIM, a + 3*DIM, s_src, s_dst);
  k_agg <<<2048, 256, 0, stream>>>(row_ptr, cse, s_src, s_dst, s_rel, B, nullptr,
                                   node, XN, out, 1);
}

// Round 9
// 474.901 us; speedup vs baseline: 5.6966x; 1.0039x over previous
//
#include <hip/hip_runtime.h>
#include <hip/hip_bf16.h>
#include <cmath>

#define NODES 150000
#define DIM 64
#define EDGES 1200000
#define NREL 32
#define NLAYERS 2
#define NND (NODES*DIM)
#define SCAN_NB ((NODES + 255)/256)   // 586
#define RBLK (NODES/16)               // 9375 row-blocks of 16

typedef __hip_bfloat16 bf16;
typedef __attribute__((ext_vector_type(8))) short bf16x8;  // MFMA A/B frag (4 VGPRs)
typedef __attribute__((ext_vector_type(4))) float f32x4;   // MFMA C/D frag

__device__ __forceinline__ float b2f(bf16 v){ return __bfloat162float(v); }
__device__ __forceinline__ short f2bs(float f){
  bf16 h = __float2bfloat16(f);
  return *(short*)&h;
}

// sentinel: encode ws_size (MB) into output (tripwire only)
__global__ void __launch_bounds__(256) k_sentinel(float* __restrict__ out, float wsmb){
  int i = blockIdx.x*256 + threadIdx.x;
  if (i < NND) out[i] = wsmb;
}

// node f32 -> bf16 working buffer; zero count[]
__global__ void __launch_bounds__(256) k_init(const float* __restrict__ node, bf16* __restrict__ x,
                                              int* __restrict__ count){
  int i = blockIdx.x*256 + threadIdx.x;
  if (i < NND) x[i] = __float2bfloat16(node[i]);
  if (i < NODES) count[i] = 0;
}

// one-time: histogram count[dst]++
__global__ void __launch_bounds__(256) k_hist(const int* __restrict__ dst, int* __restrict__ count){
  int tid0 = blockIdx.x*256 + threadIdx.x;
  int stride = gridDim.x*256;
  for (int e = tid0; e < EDGES; e += stride)
    atomicAdd(&count[dst[e]], 1);
}

// scan phase 1: per-block (256 nodes) exclusive scan + block sum
__global__ void __launch_bounds__(256) k_scan1(const int* __restrict__ count,
                                               int* __restrict__ lscan,
                                               int* __restrict__ bsum){
  int tid = threadIdx.x;
  int i = blockIdx.x*256 + tid;
  int c = (i < NODES) ? count[i] : 0;
  __shared__ int s[256];
  s[tid] = c;
  __syncthreads();
  #pragma unroll
  for (int off = 1; off < 256; off <<= 1){
    int t = (tid >= off) ? s[tid - off] : 0;
    __syncthreads();
    s[tid] += t;
    __syncthreads();
  }
  if (i < NODES) lscan[i] = s[tid] - c;
  if (tid == 255) bsum[blockIdx.x] = s[255];
}

// scan phase 2: single block scans the SCAN_NB block sums (exclusive, in place)
__global__ void __launch_bounds__(1024) k_scan2(int* __restrict__ bsum){
  int tid = threadIdx.x;
  int c = (tid < SCAN_NB) ? bsum[tid] : 0;
  __shared__ int s[1024];
  s[tid] = c;
  __syncthreads();
  #pragma unroll
  for (int off = 1; off < 1024; off <<= 1){
    int t = (tid >= off) ? s[tid - off] : 0;
    __syncthreads();
    s[tid] += t;
    __syncthreads();
  }
  if (tid < SCAN_NB) bsum[tid] = s[tid] - c;
}

// scan phase 3: row_ptr = lscan + bsum[block]; cursor copy; cap entry
__global__ void __launch_bounds__(256) k_scan3(const int* __restrict__ lscan,
                                               const int* __restrict__ bsum,
                                               int* __restrict__ row_ptr,
                                               int* __restrict__ cursor){
  int i = blockIdx.x*256 + threadIdx.x;
  if (i < NODES){
    int v = lscan[i] + bsum[i >> 8];
    row_ptr[i] = v;
    cursor[i]  = v;
  }
  if (i == NODES) row_ptr[NODES] = EDGES;
}

// one-time: scatter packed (src | et<<18) into CSR slots
__global__ void __launch_bounds__(256) k_build(const int* __restrict__ src, const int* __restrict__ dst,
                                               const int* __restrict__ et,
                                               int* __restrict__ cursor,
                                               unsigned* __restrict__ cse){
  int tid0 = blockIdx.x*256 + threadIdx.x;
  int stride = gridDim.x*256;
  for (int e = tid0; e < EDGES; e += stride){
    int p = atomicAdd(&cursor[dst[e]], 1);
    cse[p] = (unsigned)src[e] | ((unsigned)et[e] << 18);
  }
}

// per layer: s_rel[r] = rel[r] . (W_r @ a_rel)
__global__ void k_rel(const float* __restrict__ Wr_l, const float* __restrict__ a_l,
                      const float* __restrict__ rel_l, float* __restrict__ s_rel){
  __shared__ float w[DIM];
  int t = threadIdx.x; // 64 threads
  float s = 0.f;
  for (int j = 0; j < DIM; j++) s += Wr_l[t*DIM + j] * a_l[DIM + j];
  w[t] = s;
  __syncthreads();
  if (t < NREL){
    float r = 0.f;
    for (int k = 0; k < DIM; k++) r += rel_l[t*DIM + k] * w[k];
    s_rel[t] = r;
  }
}

// per layer, MFMA: xt = x @ W (bf16->bf16; in-place safe when xin==xt since the
// 16-row tile is wave-private). s_src/s_dst from accumulator registers.
// Layouts (HW-verified m89/m120): A[m=lane&15][k=(lane>>4)*8+j],
// B[k=(lane>>4)*8+j][n=lane&15], C/D: col=lane&15, row=(lane>>4)*4+reg.
__global__ void __launch_bounds__(256) k_gemm(const bf16* xin, bf16* xt,
                                              const float* __restrict__ W_l,
                                              const float* __restrict__ a_l,
                                              float* __restrict__ s_src_a,
                                              float* __restrict__ s_dst_a){
  __shared__ float Ws[DIM*DIM];   // 16 KB staged f32 W
  int tid = threadIdx.x;
  for (int i = tid; i < DIM*DIM; i += 256) Ws[i] = W_l[i];
  __syncthreads();

  int lane = tid & 63;
  int l15  = lane & 15;
  int quad = lane >> 4;

  bf16x8 bfrag[4][2];
  #pragma unroll
  for (int nt = 0; nt < 4; nt++)
    #pragma unroll
    for (int kh = 0; kh < 2; kh++)
      #pragma unroll
      for (int j = 0; j < 8; j++){
        int k = kh*32 + quad*8 + j;
        ((short*)&bfrag[nt][kh])[j] = f2bs(Ws[k*DIM + nt*16 + l15]);
      }

  float asrc[4], adst[4];
  #pragma unroll
  for (int nt = 0; nt < 4; nt++){
    asrc[nt] = a_l[nt*16 + l15];
    adst[nt] = a_l[2*DIM + nt*16 + l15];
  }

  int gw = blockIdx.x*4 + (tid >> 6);
  int nw = gridDim.x*4;
  for (int rb = gw; rb < RBLK; rb += nw){
    int r0 = rb*16;
    const size_t abase = (size_t)(r0 + l15)*DIM + quad*8;
    bf16x8 a0 = *(const bf16x8*)(xin + abase);
    bf16x8 a1 = *(const bf16x8*)(xin + abase + 32);

    f32x4 acc[4];
    #pragma unroll
    for (int nt = 0; nt < 4; nt++){
      acc[nt] = (f32x4){0.f, 0.f, 0.f, 0.f};
      acc[nt] = __builtin_amdgcn_mfma_f32_16x16x32_bf16(a0, bfrag[nt][0], acc[nt], 0, 0, 0);
      acc[nt] = __builtin_amdgcn_mfma_f32_16x16x32_bf16(a1, bfrag[nt][1], acc[nt], 0, 0, 0);
    }

    float p[4], q[4];
    #pragma unroll
    for (int i = 0; i < 4; i++){
      p[i] = acc[0][i]*asrc[0] + acc[1][i]*asrc[1] + acc[2][i]*asrc[2] + acc[3][i]*asrc[3];
      q[i] = acc[0][i]*adst[0] + acc[1][i]*adst[1] + acc[2][i]*adst[2] + acc[3][i]*adst[3];
      #pragma unroll
      for (int off = 8; off > 0; off >>= 1){
        p[i] += __shfl_xor(p[i], off, 64);
        q[i] += __shfl_xor(q[i], off, 64);
      }
    }
    if (l15 < 4){
      float pv = (l15 == 0) ? p[0] : (l15 == 1) ? p[1] : (l15 == 2) ? p[2] : p[3];
      float qv = (l15 == 0) ? q[0] : (l15 == 1) ? q[1] : (l15 == 2) ? q[2] : q[3];
      int r = r0 + quad*4 + l15;
      s_src_a[r] = pv;
      s_dst_a[r] = qv;
    }

    #pragma unroll
    for (int nt = 0; nt < 4; nt++)
      #pragma unroll
      for (int i = 0; i < 4; i++)
        xt[(size_t)(r0 + quad*4 + i)*DIM + nt*16 + l15] = __float2bfloat16(acc[nt][i]);
  }
}

// per layer, one wave per dst row. Lane-parallel scoring, then gathers batched
// in chunks of 8 (8 independent row-loads in flight before any fma use — MLP=8
// instead of 1; guards are wave-uniform so no divergence).
// mode0: write xnext only. mode1: fused finale out=(node+x1+x2)/3, no xnext.
__global__ void __launch_bounds__(256) k_agg(const int* __restrict__ row_ptr,
                                             const unsigned* __restrict__ cse,
                                             const float* __restrict__ s_src_a,
                                             const float* __restrict__ s_dst_a,
                                             const float* __restrict__ s_rel,
                                             const bf16* __restrict__ xt,
                                             bf16* __restrict__ xnext,
                                             const float* __restrict__ node,
                                             const bf16* __restrict__ x1,
                                             float* __restrict__ out, int mode){
  int lane = threadIdx.x & 63;
  int gw = blockIdx.x*4 + (threadIdx.x >> 6);
  int nw = gridDim.x*4;
  for (int row = gw; row < NODES; row += nw){
    int beg = row_ptr[row], end = row_ptr[row+1];
    float sdst = s_dst_a[row];
    float hacc = 0.f, wsuml = 0.f;
    for (int jb = beg; jb < end; jb += 64){
      int n = end - jb; if (n > 64) n = 64;
      // lane-parallel scoring: this lane's edge
      unsigned pkv = 0u;
      float wl = 0.f;
      if (lane < n){
        pkv = cse[jb + lane];
        int sl = (int)(pkv & 0x3FFFFu);
        int rl = (int)(pkv >> 18);
        float e = s_src_a[sl] + s_rel[rl] + sdst;
        e = e > 0.f ? e : 0.2f*e;
        wl = __expf(e);
      }
      wsuml += wl;
      // gather in chunks of 8: issue all loads, then consume (MLP=8)
      for (int j0 = 0; j0 < n; j0 += 8){
        int m = n - j0; if (m > 8) m = 8;
        float xv[8], wg[8];
        #pragma unroll
        for (int u = 0; u < 8; u++){
          if (u < m){
            int s  = (int)(__shfl(pkv, j0 + u, 64) & 0x3FFFFu);
            wg[u]  = __shfl(wl, j0 + u, 64);
            xv[u]  = b2f(xt[(size_t)s*DIM + lane]);
          }
        }
        #pragma unroll
        for (int u = 0; u < 8; u++)
          if (u < m) hacc = fmaf(wg[u], xv[u], hacc);
      }
    }
    // full-wave reduce of wsum
    float wsum = wsuml;
    #pragma unroll
    for (int off = 32; off > 0; off >>= 1) wsum += __shfl_xor(wsum, off, 64);

    float v = hacc / (wsum + 1e-10f);
    v = v > 0.f ? v : expm1f(v);
    float ss = v*v;
    #pragma unroll
    for (int off = 32; off > 0; off >>= 1) ss += __shfl_xor(ss, off, 64);
    float nrm = fmaxf(sqrtf(ss), 1e-12f);
    float x = v / nrm;
    int i = row*DIM + lane;
    if (mode == 0){
      xnext[i] = __float2bfloat16(x);
    } else {
      out[i] = (node[i] + b2f(x1[i]) + x) * (1.f/3.f);
    }
  }
}

extern "C" void kernel_launch(void* const* d_in, const int* in_sizes, int n_in,
                              void* d_out, int out_size, void* d_ws, size_t ws_size,
                              hipStream_t stream){
  const float* node = (const float*)d_in[0];
  const float* W    = (const float*)d_in[1];
  const float* Wr   = (const float*)d_in[2];
  const float* a    = (const float*)d_in[3];
  const float* rel  = (const float*)d_in[4];
  const int*   ei   = (const int*)d_in[5];
  const int*   et   = (const int*)d_in[6];
  const int* src = ei;
  const int* dst = ei + EDGES;
  float* out = (float*)d_out;

  // ---- workspace layout (~47 MB; proven to fit) ----
  char* w = (char*)d_ws;
  size_t off = 0;
  bf16* B  = (bf16*)(w + off); off += (size_t)NND*2;             // 19.2 MB node16/xt1, then xt2
  bf16* XN = (bf16*)(w + off); off += (size_t)NND*2;             // 19.2 MB x1 (persists through layer 1)
  unsigned* cse = (unsigned*)(w + off); off += (size_t)EDGES*4;  //  4.8 MB CSR packed (src|et<<18)
  int* row_ptr = (int*)(w + off); off += (size_t)(NODES+1)*4;    //  0.6 MB
  int* cursor  = (int*)(w + off); off += (size_t)NODES*4;        //  0.6 MB
  int* count   = (int*)(w + off); off += (size_t)NODES*4;        //  0.6 MB
  int* lscan   = (int*)(w + off); off += (size_t)NODES*4;        //  0.6 MB
  int* bsum    = (int*)(w + off); off += (size_t)SCAN_NB*4;      //  2.3 KB
  float* s_src = (float*)(w + off); off += (size_t)NODES*4;      //  0.6 MB
  float* s_dst = (float*)(w + off); off += (size_t)NODES*4;      //  0.6 MB
  float* s_rel = (float*)(w + off); off += 128;

  if (ws_size < off){
    k_sentinel<<<(NND + 255)/256, 256, 0, stream>>>(out, (float)ws_size * 1e-6f);
    return;
  }

  // one-time CSR build (layer-invariant)
  k_init <<<(NND + 255)/256, 256, 0, stream>>>(node, B, count);
  k_hist <<<4096, 256, 0, stream>>>(dst, count);
  k_scan1<<<SCAN_NB, 256, 0, stream>>>(count, lscan, bsum);
  k_scan2<<<1, 1024, 0, stream>>>(bsum);
  k_scan3<<<SCAN_NB + 1, 256, 0, stream>>>(lscan, bsum, row_ptr, cursor);
  k_build<<<4096, 256, 0, stream>>>(src, dst, et, cursor, cse);

  // layer 0: B(node bf16) -> xt1 in-place in B; x1 -> XN
  k_rel <<<1, 64, 0, stream>>>(Wr, a, rel, s_rel);
  k_gemm<<<1024, 256, 0, stream>>>(B, B, W, a, s_src, s_dst);
  k_agg <<<2048, 256, 0, stream>>>(row_ptr, cse, s_src, s_dst, s_rel, B, XN,
                                   node, XN, out, 0);

  // layer 1: XN(x1) -> xt2 in B (keeps x1); fused finale writes out
  k_rel <<<1, 64, 0, stream>>>(Wr + DIM*DIM, a + 3*DIM, rel + NREL*DIM, s_rel);
  k_gemm<<<1024, 256, 0, stream>>>(XN, B, W + DIM*DIM, a + 3*DIM, s_src, s_dst);
  k_agg <<<2048, 256, 0, stream>>>(row_ptr, cse, s_src, s_dst, s_rel, B, nullptr,
                                   node, XN, out, 1);
}

// Round 10
// 422.442 us; speedup vs baseline: 6.4040x; 1.1242x over previous
//
#include <hip/hip_runtime.h>
#include <hip/hip_bf16.h>
#include <cmath>

#define NODES 150000
#define DIM 64
#define EDGES 1200000
#define NREL 32
#define NLAYERS 2
#define NND (NODES*DIM)
#define SCAN_NB ((NODES + 255)/256)   // 586
#define RBLK (NODES/16)               // 9375 row-blocks of 16

typedef __hip_bfloat16 bf16;
typedef __attribute__((ext_vector_type(8))) short bf16x8;  // MFMA A/B frag (4 VGPRs)
typedef __attribute__((ext_vector_type(4))) float f32x4;   // MFMA C/D frag

__device__ __forceinline__ float b2f(bf16 v){ return __bfloat162float(v); }
__device__ __forceinline__ short f2bs(float f){
  bf16 h = __float2bfloat16(f);
  return *(short*)&h;
}

// sentinel: encode ws_size (MB) into output (tripwire only)
__global__ void __launch_bounds__(256) k_sentinel(float* __restrict__ out, float wsmb){
  int i = blockIdx.x*256 + threadIdx.x;
  if (i < NND) out[i] = wsmb;
}

// node f32 -> bf16 working buffer; zero count[]
__global__ void __launch_bounds__(256) k_init(const float* __restrict__ node, bf16* __restrict__ x,
                                              int* __restrict__ count){
  int i = blockIdx.x*256 + threadIdx.x;
  if (i < NND) x[i] = __float2bfloat16(node[i]);
  if (i < NODES) count[i] = 0;
}

// one-time: histogram count[dst]++
__global__ void __launch_bounds__(256) k_hist(const int* __restrict__ dst, int* __restrict__ count){
  int tid0 = blockIdx.x*256 + threadIdx.x;
  int stride = gridDim.x*256;
  for (int e = tid0; e < EDGES; e += stride)
    atomicAdd(&count[dst[e]], 1);
}

// scan phase 1: per-block (256 nodes) exclusive scan + block sum
__global__ void __launch_bounds__(256) k_scan1(const int* __restrict__ count,
                                               int* __restrict__ lscan,
                                               int* __restrict__ bsum){
  int tid = threadIdx.x;
  int i = blockIdx.x*256 + tid;
  int c = (i < NODES) ? count[i] : 0;
  __shared__ int s[256];
  s[tid] = c;
  __syncthreads();
  #pragma unroll
  for (int off = 1; off < 256; off <<= 1){
    int t = (tid >= off) ? s[tid - off] : 0;
    __syncthreads();
    s[tid] += t;
    __syncthreads();
  }
  if (i < NODES) lscan[i] = s[tid] - c;
  if (tid == 255) bsum[blockIdx.x] = s[255];
}

// scan phase 2: single block scans the SCAN_NB block sums (exclusive, in place)
__global__ void __launch_bounds__(1024) k_scan2(int* __restrict__ bsum){
  int tid = threadIdx.x;
  int c = (tid < SCAN_NB) ? bsum[tid] : 0;
  __shared__ int s[1024];
  s[tid] = c;
  __syncthreads();
  #pragma unroll
  for (int off = 1; off < 1024; off <<= 1){
    int t = (tid >= off) ? s[tid - off] : 0;
    __syncthreads();
    s[tid] += t;
    __syncthreads();
  }
  if (tid < SCAN_NB) bsum[tid] = s[tid] - c;
}

// scan phase 3: row_ptr = lscan + bsum[block]; cursor copy; cap entry
__global__ void __launch_bounds__(256) k_scan3(const int* __restrict__ lscan,
                                               const int* __restrict__ bsum,
                                               int* __restrict__ row_ptr,
                                               int* __restrict__ cursor){
  int i = blockIdx.x*256 + threadIdx.x;
  if (i < NODES){
    int v = lscan[i] + bsum[i >> 8];
    row_ptr[i] = v;
    cursor[i]  = v;
  }
  if (i == NODES) row_ptr[NODES] = EDGES;
}

// one-time: scatter packed (src | et<<18) into CSR slots
__global__ void __launch_bounds__(256) k_build(const int* __restrict__ src, const int* __restrict__ dst,
                                               const int* __restrict__ et,
                                               int* __restrict__ cursor,
                                               unsigned* __restrict__ cse){
  int tid0 = blockIdx.x*256 + threadIdx.x;
  int stride = gridDim.x*256;
  for (int e = tid0; e < EDGES; e += stride){
    int p = atomicAdd(&cursor[dst[e]], 1);
    cse[p] = (unsigned)src[e] | ((unsigned)et[e] << 18);
  }
}

// per layer: s_rel[r] = rel[r] . (W_r @ a_rel)
__global__ void k_rel(const float* __restrict__ Wr_l, const float* __restrict__ a_l,
                      const float* __restrict__ rel_l, float* __restrict__ s_rel){
  __shared__ float w[DIM];
  int t = threadIdx.x; // 64 threads
  float s = 0.f;
  for (int j = 0; j < DIM; j++) s += Wr_l[t*DIM + j] * a_l[DIM + j];
  w[t] = s;
  __syncthreads();
  if (t < NREL){
    float r = 0.f;
    for (int k = 0; k < DIM; k++) r += rel_l[t*DIM + k] * w[k];
    s_rel[t] = r;
  }
}

// per layer, MFMA: xt = x @ W (bf16->bf16; in-place safe when xin==xt since the
// 16-row tile is wave-private). s_src/s_dst from accumulator registers.
// Layouts (HW-verified m89/m120): A[m=lane&15][k=(lane>>4)*8+j],
// B[k=(lane>>4)*8+j][n=lane&15], C/D: col=lane&15, row=(lane>>4)*4+reg.
__global__ void __launch_bounds__(256) k_gemm(const bf16* xin, bf16* xt,
                                              const float* __restrict__ W_l,
                                              const float* __restrict__ a_l,
                                              float* __restrict__ s_src_a,
                                              float* __restrict__ s_dst_a){
  __shared__ float Ws[DIM*DIM];   // 16 KB staged f32 W
  int tid = threadIdx.x;
  for (int i = tid; i < DIM*DIM; i += 256) Ws[i] = W_l[i];
  __syncthreads();

  int lane = tid & 63;
  int l15  = lane & 15;
  int quad = lane >> 4;

  bf16x8 bfrag[4][2];
  #pragma unroll
  for (int nt = 0; nt < 4; nt++)
    #pragma unroll
    for (int kh = 0; kh < 2; kh++)
      #pragma unroll
      for (int j = 0; j < 8; j++){
        int k = kh*32 + quad*8 + j;
        ((short*)&bfrag[nt][kh])[j] = f2bs(Ws[k*DIM + nt*16 + l15]);
      }

  float asrc[4], adst[4];
  #pragma unroll
  for (int nt = 0; nt < 4; nt++){
    asrc[nt] = a_l[nt*16 + l15];
    adst[nt] = a_l[2*DIM + nt*16 + l15];
  }

  int gw = blockIdx.x*4 + (tid >> 6);
  int nw = gridDim.x*4;
  for (int rb = gw; rb < RBLK; rb += nw){
    int r0 = rb*16;
    const size_t abase = (size_t)(r0 + l15)*DIM + quad*8;
    bf16x8 a0 = *(const bf16x8*)(xin + abase);
    bf16x8 a1 = *(const bf16x8*)(xin + abase + 32);

    f32x4 acc[4];
    #pragma unroll
    for (int nt = 0; nt < 4; nt++){
      acc[nt] = (f32x4){0.f, 0.f, 0.f, 0.f};
      acc[nt] = __builtin_amdgcn_mfma_f32_16x16x32_bf16(a0, bfrag[nt][0], acc[nt], 0, 0, 0);
      acc[nt] = __builtin_amdgcn_mfma_f32_16x16x32_bf16(a1, bfrag[nt][1], acc[nt], 0, 0, 0);
    }

    float p[4], q[4];
    #pragma unroll
    for (int i = 0; i < 4; i++){
      p[i] = acc[0][i]*asrc[0] + acc[1][i]*asrc[1] + acc[2][i]*asrc[2] + acc[3][i]*asrc[3];
      q[i] = acc[0][i]*adst[0] + acc[1][i]*adst[1] + acc[2][i]*adst[2] + acc[3][i]*adst[3];
      #pragma unroll
      for (int off = 8; off > 0; off >>= 1){
        p[i] += __shfl_xor(p[i], off, 64);
        q[i] += __shfl_xor(q[i], off, 64);
      }
    }
    if (l15 < 4){
      float pv = (l15 == 0) ? p[0] : (l15 == 1) ? p[1] : (l15 == 2) ? p[2] : p[3];
      float qv = (l15 == 0) ? q[0] : (l15 == 1) ? q[1] : (l15 == 2) ? q[2] : q[3];
      int r = r0 + quad*4 + l15;
      s_src_a[r] = pv;
      s_dst_a[r] = qv;
    }

    #pragma unroll
    for (int nt = 0; nt < 4; nt++)
      #pragma unroll
      for (int i = 0; i < 4; i++)
        xt[(size_t)(r0 + quad*4 + i)*DIM + nt*16 + l15] = __float2bfloat16(acc[nt][i]);
  }
}

// per layer, one wave per dst row. Lane-parallel scoring; gather loop is
// GUARD-FREE 8-unrolled: lanes >= n carry (pkv=0, wl=0), so over-read slots
// broadcast weight 0 / src 0 (benign cached row-0 load x 0). No exec-mask ops
// in the body -> compiler keeps all 8 gathers in flight (MLP=8).
// mode0: write xnext only. mode1: fused finale out=(node+x1+x2)/3, no xnext.
__global__ void __launch_bounds__(256) k_agg(const int* __restrict__ row_ptr,
                                             const unsigned* __restrict__ cse,
                                             const float* __restrict__ s_src_a,
                                             const float* __restrict__ s_dst_a,
                                             const float* __restrict__ s_rel,
                                             const bf16* __restrict__ xt,
                                             bf16* __restrict__ xnext,
                                             const float* __restrict__ node,
                                             const bf16* __restrict__ x1,
                                             float* __restrict__ out, int mode){
  int lane = threadIdx.x & 63;
  int gw = blockIdx.x*4 + (threadIdx.x >> 6);
  int nw = gridDim.x*4;
  for (int row = gw; row < NODES; row += nw){
    int beg = row_ptr[row], end = row_ptr[row+1];
    float sdst = s_dst_a[row];
    float hacc = 0.f, wsuml = 0.f;
    for (int jb = beg; jb < end; jb += 64){
      int n = end - jb; if (n > 64) n = 64;
      // lane-parallel scoring: this lane's edge (lanes >= n: pkv=0, wl=0)
      unsigned pkv = 0u;
      float wl = 0.f;
      if (lane < n){
        pkv = cse[jb + lane];
        int sl = (int)(pkv & 0x3FFFFu);
        int rl = (int)(pkv >> 18);
        float e = s_src_a[sl] + s_rel[rl] + sdst;
        e = e > 0.f ? e : 0.2f*e;
        wl = __expf(e);
      }
      wsuml += wl;
      // guard-free gather, 8 loads in flight per chunk
      int nk = (n + 7) & ~7;
      for (int j0 = 0; j0 < nk; j0 += 8){
        float xv[8], wg[8];
        #pragma unroll
        for (int u = 0; u < 8; u++){
          int s  = (int)(__shfl(pkv, j0 + u, 64) & 0x3FFFFu);
          wg[u]  = __shfl(wl, j0 + u, 64);
          xv[u]  = b2f(xt[(size_t)s*DIM + lane]);
        }
        #pragma unroll
        for (int u = 0; u < 8; u++)
          hacc = fmaf(wg[u], xv[u], hacc);
      }
    }
    // full-wave reduce of wsum
    float wsum = wsuml;
    #pragma unroll
    for (int off = 32; off > 0; off >>= 1) wsum += __shfl_xor(wsum, off, 64);

    float v = hacc / (wsum + 1e-10f);
    v = v > 0.f ? v : expm1f(v);
    float ss = v*v;
    #pragma unroll
    for (int off = 32; off > 0; off >>= 1) ss += __shfl_xor(ss, off, 64);
    float nrm = fmaxf(sqrtf(ss), 1e-12f);
    float x = v / nrm;
    int i = row*DIM + lane;
    if (mode == 0){
      xnext[i] = __float2bfloat16(x);
    } else {
      out[i] = (node[i] + b2f(x1[i]) + x) * (1.f/3.f);
    }
  }
}

extern "C" void kernel_launch(void* const* d_in, const int* in_sizes, int n_in,
                              void* d_out, int out_size, void* d_ws, size_t ws_size,
                              hipStream_t stream){
  const float* node = (const float*)d_in[0];
  const float* W    = (const float*)d_in[1];
  const float* Wr   = (const float*)d_in[2];
  const float* a    = (const float*)d_in[3];
  const float* rel  = (const float*)d_in[4];
  const int*   ei   = (const int*)d_in[5];
  const int*   et   = (const int*)d_in[6];
  const int* src = ei;
  const int* dst = ei + EDGES;
  float* out = (float*)d_out;

  // ---- workspace layout (~47 MB; proven to fit) ----
  char* w = (char*)d_ws;
  size_t off = 0;
  bf16* B  = (bf16*)(w + off); off += (size_t)NND*2;             // 19.2 MB node16/xt1, then xt2
  bf16* XN = (bf16*)(w + off); off += (size_t)NND*2;             // 19.2 MB x1 (persists through layer 1)
  unsigned* cse = (unsigned*)(w + off); off += (size_t)EDGES*4;  //  4.8 MB CSR packed (src|et<<18)
  int* row_ptr = (int*)(w + off); off += (size_t)(NODES+1)*4;    //  0.6 MB
  int* cursor  = (int*)(w + off); off += (size_t)NODES*4;        //  0.6 MB
  int* count   = (int*)(w + off); off += (size_t)NODES*4;        //  0.6 MB
  int* lscan   = (int*)(w + off); off += (size_t)NODES*4;        //  0.6 MB
  int* bsum    = (int*)(w + off); off += (size_t)SCAN_NB*4;      //  2.3 KB
  float* s_src = (float*)(w + off); off += (size_t)NODES*4;      //  0.6 MB
  float* s_dst = (float*)(w + off); off += (size_t)NODES*4;      //  0.6 MB
  float* s_rel = (float*)(w + off); off += 128;

  if (ws_size < off){
    k_sentinel<<<(NND + 255)/256, 256, 0, stream>>>(out, (float)ws_size * 1e-6f);
    return;
  }

  // one-time CSR build (layer-invariant)
  k_init <<<(NND + 255)/256, 256, 0, stream>>>(node, B, count);
  k_hist <<<4096, 256, 0, stream>>>(dst, count);
  k_scan1<<<SCAN_NB, 256, 0, stream>>>(count, lscan, bsum);
  k_scan2<<<1, 1024, 0, stream>>>(bsum);
  k_scan3<<<SCAN_NB + 1, 256, 0, stream>>>(lscan, bsum, row_ptr, cursor);
  k_build<<<4096, 256, 0, stream>>>(src, dst, et, cursor, cse);

  // layer 0: B(node bf16) -> xt1 in-place in B; x1 -> XN
  k_rel <<<1, 64, 0, stream>>>(Wr, a, rel, s_rel);
  k_gemm<<<1024, 256, 0, stream>>>(B, B, W, a, s_src, s_dst);
  k_agg <<<2048, 256, 0, stream>>>(row_ptr, cse, s_src, s_dst, s_rel, B, XN,
                                   node, XN, out, 0);

  // layer 1: XN(x1) -> xt2 in B (keeps x1); fused finale writes out
  k_rel <<<1, 64, 0, stream>>>(Wr + DIM*DIM, a + 3*DIM, rel + NREL*DIM, s_rel);
  k_gemm<<<1024, 256, 0, stream>>>(XN, B, W + DIM*DIM, a + 3*DIM, s_src, s_dst);
  k_agg <<<2048, 256, 0, stream>>>(row_ptr, cse, s_src, s_dst, s_rel, B, nullptr,
                                   node, XN, out, 1);
}

// Round 11
// 351.167 us; speedup vs baseline: 7.7038x; 1.2030x over previous
//
#include <hip/hip_runtime.h>
#include <hip/hip_bf16.h>
#include <cmath>

#define NODES 150000
#define DIM 64
#define EDGES 1200000
#define NREL 32
#define NLAYERS 2
#define NND (NODES*DIM)
#define SCAN_NB ((NODES + 255)/256)   // 586
#define RBLK (NODES/16)               // 9375 row-blocks of 16

typedef __hip_bfloat16 bf16;
typedef unsigned short ushort16;
typedef __attribute__((ext_vector_type(8))) short bf16x8;  // MFMA A/B frag (4 VGPRs)
typedef __attribute__((ext_vector_type(4))) float f32x4;   // MFMA C/D frag

__device__ __forceinline__ float b2f(bf16 v){ return __bfloat162float(v); }
__device__ __forceinline__ short f2bs(float f){
  bf16 h = __float2bfloat16(f);
  return *(short*)&h;
}

// sentinel: encode ws_size (MB) into output (tripwire only)
__global__ void __launch_bounds__(256) k_sentinel(float* __restrict__ out, float wsmb){
  int i = blockIdx.x*256 + threadIdx.x;
  if (i < NND) out[i] = wsmb;
}

// fused: node f32 -> bf16 convert  +  single-atomic-pass histogram that also
// records each edge's local slot pl[e] (the atomic's return value). count[]
// must be pre-zeroed (memsetAsync). Convert is BW-bound, hist is atomic-bound
// -> fused they overlap pipes.
__global__ void __launch_bounds__(256) k_inithist(const float* __restrict__ node,
                                                  bf16* __restrict__ x,
                                                  const int* __restrict__ dst,
                                                  int* __restrict__ count,
                                                  ushort16* __restrict__ pl){
  int tid0 = blockIdx.x*256 + threadIdx.x;
  int stride = gridDim.x*256;
  for (int i = tid0; i < NND; i += stride) x[i] = __float2bfloat16(node[i]);
  for (int e = tid0; e < EDGES; e += stride)
    pl[e] = (ushort16)atomicAdd(&count[dst[e]], 1);
}

// scan phase 1: per-block (256 nodes) exclusive scan + block sum
__global__ void __launch_bounds__(256) k_scan1(const int* __restrict__ count,
                                               int* __restrict__ lscan,
                                               int* __restrict__ bsum){
  int tid = threadIdx.x;
  int i = blockIdx.x*256 + tid;
  int c = (i < NODES) ? count[i] : 0;
  __shared__ int s[256];
  s[tid] = c;
  __syncthreads();
  #pragma unroll
  for (int off = 1; off < 256; off <<= 1){
    int t = (tid >= off) ? s[tid - off] : 0;
    __syncthreads();
    s[tid] += t;
    __syncthreads();
  }
  if (i < NODES) lscan[i] = s[tid] - c;
  if (tid == 255) bsum[blockIdx.x] = s[255];
}

// scan phase 2: single block scans the SCAN_NB block sums (exclusive, in place)
__global__ void __launch_bounds__(1024) k_scan2(int* __restrict__ bsum){
  int tid = threadIdx.x;
  int c = (tid < SCAN_NB) ? bsum[tid] : 0;
  __shared__ int s[1024];
  s[tid] = c;
  __syncthreads();
  #pragma unroll
  for (int off = 1; off < 1024; off <<= 1){
    int t = (tid >= off) ? s[tid - off] : 0;
    __syncthreads();
    s[tid] += t;
    __syncthreads();
  }
  if (tid < SCAN_NB) bsum[tid] = s[tid] - c;
}

// scan phase 3: row_ptr = lscan + bsum[block]; cap entry (no cursor needed)
__global__ void __launch_bounds__(256) k_scan3(const int* __restrict__ lscan,
                                               const int* __restrict__ bsum,
                                               int* __restrict__ row_ptr){
  int i = blockIdx.x*256 + threadIdx.x;
  if (i < NODES) row_ptr[i] = lscan[i] + bsum[i >> 8];
  if (i == NODES) row_ptr[NODES] = EDGES;
}

// atomic-free scatter: p = row_ptr[dst] + pl (unique). row_ptr gather is a
// 0.6 MB L2-resident table; cse store is the only inherent scatter left.
__global__ void __launch_bounds__(256) k_build(const int* __restrict__ src,
                                               const int* __restrict__ dst,
                                               const int* __restrict__ et,
                                               const ushort16* __restrict__ pl,
                                               const int* __restrict__ row_ptr,
                                               unsigned* __restrict__ cse){
  int tid0 = blockIdx.x*256 + threadIdx.x;
  int stride = gridDim.x*256;
  for (int e = tid0; e < EDGES; e += stride){
    int p = row_ptr[dst[e]] + (int)pl[e];
    cse[p] = (unsigned)src[e] | ((unsigned)et[e] << 18);
  }
}

// both layers' s_rel in one launch: block l computes s_rel[l][r]
__global__ void k_relboth(const float* __restrict__ Wr, const float* __restrict__ a,
                          const float* __restrict__ rel, float* __restrict__ s_rel){
  int l = blockIdx.x;
  const float* Wr_l  = Wr  + l*DIM*DIM;
  const float* a_l   = a   + l*3*DIM;
  const float* rel_l = rel + l*NREL*DIM;
  __shared__ float w[DIM];
  int t = threadIdx.x; // 64 threads
  float s = 0.f;
  for (int j = 0; j < DIM; j++) s += Wr_l[t*DIM + j] * a_l[DIM + j];
  w[t] = s;
  __syncthreads();
  if (t < NREL){
    float r = 0.f;
    for (int k = 0; k < DIM; k++) r += rel_l[t*DIM + k] * w[k];
    s_rel[l*NREL + t] = r;
  }
}

// per layer, MFMA: xt = x @ W (bf16->bf16; in-place safe when xin==xt since the
// 16-row tile is wave-private). s_src/s_dst from accumulator registers.
// Layouts (HW-verified m89/m120): A[m=lane&15][k=(lane>>4)*8+j],
// B[k=(lane>>4)*8+j][n=lane&15], C/D: col=lane&15, row=(lane>>4)*4+reg.
__global__ void __launch_bounds__(256) k_gemm(const bf16* xin, bf16* xt,
                                              const float* __restrict__ W_l,
                                              const float* __restrict__ a_l,
                                              float* __restrict__ s_src_a,
                                              float* __restrict__ s_dst_a){
  __shared__ float Ws[DIM*DIM];   // 16 KB staged f32 W
  int tid = threadIdx.x;
  for (int i = tid; i < DIM*DIM; i += 256) Ws[i] = W_l[i];
  __syncthreads();

  int lane = tid & 63;
  int l15  = lane & 15;
  int quad = lane >> 4;

  bf16x8 bfrag[4][2];
  #pragma unroll
  for (int nt = 0; nt < 4; nt++)
    #pragma unroll
    for (int kh = 0; kh < 2; kh++)
      #pragma unroll
      for (int j = 0; j < 8; j++){
        int k = kh*32 + quad*8 + j;
        ((short*)&bfrag[nt][kh])[j] = f2bs(Ws[k*DIM + nt*16 + l15]);
      }

  float asrc[4], adst[4];
  #pragma unroll
  for (int nt = 0; nt < 4; nt++){
    asrc[nt] = a_l[nt*16 + l15];
    adst[nt] = a_l[2*DIM + nt*16 + l15];
  }

  int gw = blockIdx.x*4 + (tid >> 6);
  int nw = gridDim.x*4;
  for (int rb = gw; rb < RBLK; rb += nw){
    int r0 = rb*16;
    const size_t abase = (size_t)(r0 + l15)*DIM + quad*8;
    bf16x8 a0 = *(const bf16x8*)(xin + abase);
    bf16x8 a1 = *(const bf16x8*)(xin + abase + 32);

    f32x4 acc[4];
    #pragma unroll
    for (int nt = 0; nt < 4; nt++){
      acc[nt] = (f32x4){0.f, 0.f, 0.f, 0.f};
      acc[nt] = __builtin_amdgcn_mfma_f32_16x16x32_bf16(a0, bfrag[nt][0], acc[nt], 0, 0, 0);
      acc[nt] = __builtin_amdgcn_mfma_f32_16x16x32_bf16(a1, bfrag[nt][1], acc[nt], 0, 0, 0);
    }

    float p[4], q[4];
    #pragma unroll
    for (int i = 0; i < 4; i++){
      p[i] = acc[0][i]*asrc[0] + acc[1][i]*asrc[1] + acc[2][i]*asrc[2] + acc[3][i]*asrc[3];
      q[i] = acc[0][i]*adst[0] + acc[1][i]*adst[1] + acc[2][i]*adst[2] + acc[3][i]*adst[3];
      #pragma unroll
      for (int off = 8; off > 0; off >>= 1){
        p[i] += __shfl_xor(p[i], off, 64);
        q[i] += __shfl_xor(q[i], off, 64);
      }
    }
    if (l15 < 4){
      float pv = (l15 == 0) ? p[0] : (l15 == 1) ? p[1] : (l15 == 2) ? p[2] : p[3];
      float qv = (l15 == 0) ? q[0] : (l15 == 1) ? q[1] : (l15 == 2) ? q[2] : q[3];
      int r = r0 + quad*4 + l15;
      s_src_a[r] = pv;
      s_dst_a[r] = qv;
    }

    #pragma unroll
    for (int nt = 0; nt < 4; nt++)
      #pragma unroll
      for (int i = 0; i < 4; i++)
        xt[(size_t)(r0 + quad*4 + i)*DIM + nt*16 + l15] = __float2bfloat16(acc[nt][i]);
  }
}

// per layer, one wave per dst row. Lane-parallel scoring; guard-free 8-unrolled
// gather (lanes >= n carry pkv=0, wl=0 -> benign weight-0 row-0 loads; no
// exec-mask ops -> MLP=8).
// mode0: write xnext only. mode1: fused finale out=(node+x1+x2)/3, no xnext.
__global__ void __launch_bounds__(256) k_agg(const int* __restrict__ row_ptr,
                                             const unsigned* __restrict__ cse,
                                             const float* __restrict__ s_src_a,
                                             const float* __restrict__ s_dst_a,
                                             const float* __restrict__ s_rel,
                                             const bf16* __restrict__ xt,
                                             bf16* __restrict__ xnext,
                                             const float* __restrict__ node,
                                             const bf16* __restrict__ x1,
                                             float* __restrict__ out, int mode){
  int lane = threadIdx.x & 63;
  int gw = blockIdx.x*4 + (threadIdx.x >> 6);
  int nw = gridDim.x*4;
  for (int row = gw; row < NODES; row += nw){
    int beg = row_ptr[row], end = row_ptr[row+1];
    float sdst = s_dst_a[row];
    float hacc = 0.f, wsuml = 0.f;
    for (int jb = beg; jb < end; jb += 64){
      int n = end - jb; if (n > 64) n = 64;
      unsigned pkv = 0u;
      float wl = 0.f;
      if (lane < n){
        pkv = cse[jb + lane];
        int sl = (int)(pkv & 0x3FFFFu);
        int rl = (int)(pkv >> 18);
        float e = s_src_a[sl] + s_rel[rl] + sdst;
        e = e > 0.f ? e : 0.2f*e;
        wl = __expf(e);
      }
      wsuml += wl;
      int nk = (n + 7) & ~7;
      for (int j0 = 0; j0 < nk; j0 += 8){
        float xv[8], wg[8];
        #pragma unroll
        for (int u = 0; u < 8; u++){
          int s  = (int)(__shfl(pkv, j0 + u, 64) & 0x3FFFFu);
          wg[u]  = __shfl(wl, j0 + u, 64);
          xv[u]  = b2f(xt[(size_t)s*DIM + lane]);
        }
        #pragma unroll
        for (int u = 0; u < 8; u++)
          hacc = fmaf(wg[u], xv[u], hacc);
      }
    }
    float wsum = wsuml;
    #pragma unroll
    for (int off = 32; off > 0; off >>= 1) wsum += __shfl_xor(wsum, off, 64);

    float v = hacc / (wsum + 1e-10f);
    v = v > 0.f ? v : expm1f(v);
    float ss = v*v;
    #pragma unroll
    for (int off = 32; off > 0; off >>= 1) ss += __shfl_xor(ss, off, 64);
    float nrm = fmaxf(sqrtf(ss), 1e-12f);
    float x = v / nrm;
    int i = row*DIM + lane;
    if (mode == 0){
      xnext[i] = __float2bfloat16(x);
    } else {
      out[i] = (node[i] + b2f(x1[i]) + x) * (1.f/3.f);
    }
  }
}

extern "C" void kernel_launch(void* const* d_in, const int* in_sizes, int n_in,
                              void* d_out, int out_size, void* d_ws, size_t ws_size,
                              hipStream_t stream){
  const float* node = (const float*)d_in[0];
  const float* W    = (const float*)d_in[1];
  const float* Wr   = (const float*)d_in[2];
  const float* a    = (const float*)d_in[3];
  const float* rel  = (const float*)d_in[4];
  const int*   ei   = (const int*)d_in[5];
  const int*   et   = (const int*)d_in[6];
  const int* src = ei;
  const int* dst = ei + EDGES;
  float* out = (float*)d_out;

  // ---- workspace layout (~48 MB; proven to fit) ----
  char* w = (char*)d_ws;
  size_t off = 0;
  bf16* B  = (bf16*)(w + off); off += (size_t)NND*2;             // 19.2 MB node16/xt1, then xt2
  bf16* XN = (bf16*)(w + off); off += (size_t)NND*2;             // 19.2 MB x1 (persists through layer 1)
  unsigned* cse = (unsigned*)(w + off); off += (size_t)EDGES*4;  //  4.8 MB CSR packed (src|et<<18)
  ushort16* pl = (ushort16*)(w + off); off += (size_t)EDGES*2;   //  2.4 MB per-edge local slot
  int* row_ptr = (int*)(w + off); off += (size_t)(NODES+1)*4;    //  0.6 MB
  int* count   = (int*)(w + off); off += (size_t)NODES*4;        //  0.6 MB
  int* lscan   = (int*)(w + off); off += (size_t)NODES*4;        //  0.6 MB
  int* bsum    = (int*)(w + off); off += (size_t)SCAN_NB*4;      //  2.3 KB
  float* s_src = (float*)(w + off); off += (size_t)NODES*4;      //  0.6 MB
  float* s_dst = (float*)(w + off); off += (size_t)NODES*4;      //  0.6 MB
  float* s_rel = (float*)(w + off); off += 2*NREL*4;

  if (ws_size < off){
    k_sentinel<<<(NND + 255)/256, 256, 0, stream>>>(out, (float)ws_size * 1e-6f);
    return;
  }

  // one-time CSR build (layer-invariant), single atomic pass
  hipMemsetAsync(count, 0, (size_t)NODES*4, stream);
  k_relboth <<<2, 64, 0, stream>>>(Wr, a, rel, s_rel);
  k_inithist<<<4096, 256, 0, stream>>>(node, B, dst, count, pl);
  k_scan1   <<<SCAN_NB, 256, 0, stream>>>(count, lscan, bsum);
  k_scan2   <<<1, 1024, 0, stream>>>(bsum);
  k_scan3   <<<SCAN_NB + 1, 256, 0, stream>>>(lscan, bsum, row_ptr);
  k_build   <<<4096, 256, 0, stream>>>(src, dst, et, pl, row_ptr, cse);

  // layer 0: B(node bf16) -> xt1 in-place in B; x1 -> XN
  k_gemm<<<1024, 256, 0, stream>>>(B, B, W, a, s_src, s_dst);
  k_agg <<<2048, 256, 0, stream>>>(row_ptr, cse, s_src, s_dst, s_rel, B, XN,
                                   node, XN, out, 0);

  // layer 1: XN(x1) -> xt2 in B (keeps x1); fused finale writes out
  k_gemm<<<1024, 256, 0, stream>>>(XN, B, W + DIM*DIM, a + 3*DIM, s_src, s_dst);
  k_agg <<<2048, 256, 0, stream>>>(row_ptr, cse, s_src, s_dst, s_rel + NREL, B, nullptr,
                                   node, XN, out, 1);
}

// Round 12
// 288.338 us; speedup vs baseline: 9.3825x; 1.2179x over previous
//
#include <hip/hip_runtime.h>
#include <hip/hip_bf16.h>
#include <cmath>

#define NODES 150000
#define DIM 64
#define EDGES 1200000
#define NREL 32
#define NLAYERS 2
#define NND (NODES*DIM)
#define SCAN_NB ((NODES + 255)/256)   // 586
#define RBLK (NODES/16)               // 9375 row-blocks of 16 (gemm)
#define NRB4 (NODES/4)                // 37500 row-quads (agg)

typedef __hip_bfloat16 bf16;
typedef unsigned short ushort16;
typedef __attribute__((ext_vector_type(8))) short bf16x8;  // MFMA A/B frag (4 VGPRs)
typedef __attribute__((ext_vector_type(4))) float f32x4;   // MFMA C/D frag

__device__ __forceinline__ float b2f(bf16 v){ return __bfloat162float(v); }
__device__ __forceinline__ short f2bs(float f){
  bf16 h = __float2bfloat16(f);
  return *(short*)&h;
}

// sentinel: encode ws_size (MB) into output (tripwire only)
__global__ void __launch_bounds__(256) k_sentinel(float* __restrict__ out, float wsmb){
  int i = blockIdx.x*256 + threadIdx.x;
  if (i < NND) out[i] = wsmb;
}

// fused: node f32 -> bf16 convert + single-atomic-pass histogram recording
// each edge's local slot pl[e] (atomic return value). count[] pre-zeroed.
__global__ void __launch_bounds__(256) k_inithist(const float* __restrict__ node,
                                                  bf16* __restrict__ x,
                                                  const int* __restrict__ dst,
                                                  int* __restrict__ count,
                                                  ushort16* __restrict__ pl){
  int tid0 = blockIdx.x*256 + threadIdx.x;
  int stride = gridDim.x*256;
  for (int i = tid0; i < NND; i += stride) x[i] = __float2bfloat16(node[i]);
  for (int e = tid0; e < EDGES; e += stride)
    pl[e] = (ushort16)atomicAdd(&count[dst[e]], 1);
}

// scan phase 1: per-block (256 nodes) exclusive scan + block sum
__global__ void __launch_bounds__(256) k_scan1(const int* __restrict__ count,
                                               int* __restrict__ lscan,
                                               int* __restrict__ bsum){
  int tid = threadIdx.x;
  int i = blockIdx.x*256 + tid;
  int c = (i < NODES) ? count[i] : 0;
  __shared__ int s[256];
  s[tid] = c;
  __syncthreads();
  #pragma unroll
  for (int off = 1; off < 256; off <<= 1){
    int t = (tid >= off) ? s[tid - off] : 0;
    __syncthreads();
    s[tid] += t;
    __syncthreads();
  }
  if (i < NODES) lscan[i] = s[tid] - c;
  if (tid == 255) bsum[blockIdx.x] = s[255];
}

// scan phase 2: single block scans the SCAN_NB block sums (exclusive, in place)
__global__ void __launch_bounds__(1024) k_scan2(int* __restrict__ bsum){
  int tid = threadIdx.x;
  int c = (tid < SCAN_NB) ? bsum[tid] : 0;
  __shared__ int s[1024];
  s[tid] = c;
  __syncthreads();
  #pragma unroll
  for (int off = 1; off < 1024; off <<= 1){
    int t = (tid >= off) ? s[tid - off] : 0;
    __syncthreads();
    s[tid] += t;
    __syncthreads();
  }
  if (tid < SCAN_NB) bsum[tid] = s[tid] - c;
}

// scan phase 3: row_ptr = lscan + bsum[block]; cap entry
__global__ void __launch_bounds__(256) k_scan3(const int* __restrict__ lscan,
                                               const int* __restrict__ bsum,
                                               int* __restrict__ row_ptr){
  int i = blockIdx.x*256 + threadIdx.x;
  if (i < NODES) row_ptr[i] = lscan[i] + bsum[i >> 8];
  if (i == NODES) row_ptr[NODES] = EDGES;
}

// atomic-free scatter: p = row_ptr[dst] + pl (unique)
__global__ void __launch_bounds__(256) k_build(const int* __restrict__ src,
                                               const int* __restrict__ dst,
                                               const int* __restrict__ et,
                                               const ushort16* __restrict__ pl,
                                               const int* __restrict__ row_ptr,
                                               unsigned* __restrict__ cse){
  int tid0 = blockIdx.x*256 + threadIdx.x;
  int stride = gridDim.x*256;
  for (int e = tid0; e < EDGES; e += stride){
    int p = row_ptr[dst[e]] + (int)pl[e];
    cse[p] = (unsigned)src[e] | ((unsigned)et[e] << 18);
  }
}

// both layers' s_rel in one launch: block l computes s_rel[l][r]
__global__ void k_relboth(const float* __restrict__ Wr, const float* __restrict__ a,
                          const float* __restrict__ rel, float* __restrict__ s_rel){
  int l = blockIdx.x;
  const float* Wr_l  = Wr  + l*DIM*DIM;
  const float* a_l   = a   + l*3*DIM;
  const float* rel_l = rel + l*NREL*DIM;
  __shared__ float w[DIM];
  int t = threadIdx.x; // 64 threads
  float s = 0.f;
  for (int j = 0; j < DIM; j++) s += Wr_l[t*DIM + j] * a_l[DIM + j];
  w[t] = s;
  __syncthreads();
  if (t < NREL){
    float r = 0.f;
    for (int k = 0; k < DIM; k++) r += rel_l[t*DIM + k] * w[k];
    s_rel[l*NREL + t] = r;
  }
}

// per layer, MFMA: xt = x @ W (bf16->bf16; in-place safe when xin==xt since the
// 16-row tile is wave-private). s_src/s_dst from accumulator registers.
__global__ void __launch_bounds__(256) k_gemm(const bf16* xin, bf16* xt,
                                              const float* __restrict__ W_l,
                                              const float* __restrict__ a_l,
                                              float* __restrict__ s_src_a,
                                              float* __restrict__ s_dst_a){
  __shared__ float Ws[DIM*DIM];   // 16 KB staged f32 W
  int tid = threadIdx.x;
  for (int i = tid; i < DIM*DIM; i += 256) Ws[i] = W_l[i];
  __syncthreads();

  int lane = tid & 63;
  int l15  = lane & 15;
  int quad = lane >> 4;

  bf16x8 bfrag[4][2];
  #pragma unroll
  for (int nt = 0; nt < 4; nt++)
    #pragma unroll
    for (int kh = 0; kh < 2; kh++)
      #pragma unroll
      for (int j = 0; j < 8; j++){
        int k = kh*32 + quad*8 + j;
        ((short*)&bfrag[nt][kh])[j] = f2bs(Ws[k*DIM + nt*16 + l15]);
      }

  float asrc[4], adst[4];
  #pragma unroll
  for (int nt = 0; nt < 4; nt++){
    asrc[nt] = a_l[nt*16 + l15];
    adst[nt] = a_l[2*DIM + nt*16 + l15];
  }

  int gw = blockIdx.x*4 + (tid >> 6);
  int nw = gridDim.x*4;
  for (int rb = gw; rb < RBLK; rb += nw){
    int r0 = rb*16;
    const size_t abase = (size_t)(r0 + l15)*DIM + quad*8;
    bf16x8 a0 = *(const bf16x8*)(xin + abase);
    bf16x8 a1 = *(const bf16x8*)(xin + abase + 32);

    f32x4 acc[4];
    #pragma unroll
    for (int nt = 0; nt < 4; nt++){
      acc[nt] = (f32x4){0.f, 0.f, 0.f, 0.f};
      acc[nt] = __builtin_amdgcn_mfma_f32_16x16x32_bf16(a0, bfrag[nt][0], acc[nt], 0, 0, 0);
      acc[nt] = __builtin_amdgcn_mfma_f32_16x16x32_bf16(a1, bfrag[nt][1], acc[nt], 0, 0, 0);
    }

    float p[4], q[4];
    #pragma unroll
    for (int i = 0; i < 4; i++){
      p[i] = acc[0][i]*asrc[0] + acc[1][i]*asrc[1] + acc[2][i]*asrc[2] + acc[3][i]*asrc[3];
      q[i] = acc[0][i]*adst[0] + acc[1][i]*adst[1] + acc[2][i]*adst[2] + acc[3][i]*adst[3];
      #pragma unroll
      for (int off = 8; off > 0; off >>= 1){
        p[i] += __shfl_xor(p[i], off, 64);
        q[i] += __shfl_xor(q[i], off, 64);
      }
    }
    if (l15 < 4){
      float pv = (l15 == 0) ? p[0] : (l15 == 1) ? p[1] : (l15 == 2) ? p[2] : p[3];
      float qv = (l15 == 0) ? q[0] : (l15 == 1) ? q[1] : (l15 == 2) ? q[2] : q[3];
      int r = r0 + quad*4 + l15;
      s_src_a[r] = pv;
      s_dst_a[r] = qv;
    }

    #pragma unroll
    for (int nt = 0; nt < 4; nt++)
      #pragma unroll
      for (int i = 0; i < 4; i++)
        xt[(size_t)(r0 + quad*4 + i)*DIM + nt*16 + l15] = __float2bfloat16(acc[nt][i]);
  }
}

// per layer: FOUR rows per wave (16-lane groups). Lane l15 of group grp covers
// columns [l15*4, l15*4+4) of row rb*4+grp. Per edge: one 8 B load (4 bf16)
// feeds 4 fmas; 2 shfls serve the whole group. 4 independent row chains per
// wave + MLP=4 gathers per group = 16 loads in flight per wave.
// Guard-free: idle scoring lanes carry wl=0 -> weight-0 row-0 gathers.
// All shfl sources stay inside the lane's own (active) group, so inter-group
// trip-count divergence is safe.
// mode0: write xnext only. mode1: fused finale out=(node+x1+x2)/3, no xnext.
__global__ void __launch_bounds__(256) k_agg(const int* __restrict__ row_ptr,
                                             const unsigned* __restrict__ cse,
                                             const float* __restrict__ s_src_a,
                                             const float* __restrict__ s_dst_a,
                                             const float* __restrict__ s_rel,
                                             const bf16* __restrict__ xt,
                                             bf16* __restrict__ xnext,
                                             const float* __restrict__ node,
                                             const bf16* __restrict__ x1,
                                             float* __restrict__ out, int mode){
  int lane = threadIdx.x & 63;
  int grp  = lane >> 4;
  int l15  = lane & 15;
  int gw = blockIdx.x*4 + (threadIdx.x >> 6);
  int nw = gridDim.x*4;
  for (int rb = gw; rb < NRB4; rb += nw){
    int row = rb*4 + grp;
    int beg = row_ptr[row], end = row_ptr[row+1];
    float sdst = s_dst_a[row];
    float h0 = 0.f, h1 = 0.f, h2 = 0.f, h3 = 0.f;
    float wsuml = 0.f;
    for (int jb = beg; jb < end; jb += 16){
      int n = end - jb; if (n > 16) n = 16;
      unsigned pkv = 0u; float wl = 0.f;
      if (l15 < n){
        pkv = cse[jb + l15];
        int sl = (int)(pkv & 0x3FFFFu);
        int rl = (int)(pkv >> 18);
        float e = s_src_a[sl] + s_rel[rl] + sdst;
        e = e > 0.f ? e : 0.2f*e;
        wl = __expf(e);
      }
      wsuml += wl;
      int nk = (n + 3) & ~3;
      for (int j0 = 0; j0 < nk; j0 += 4){
        unsigned lo[4], hi[4];
        float wg[4];
        #pragma unroll
        for (int u = 0; u < 4; u++){
          int srcl = grp*16 + j0 + u;               // within this lane's group
          int s    = (int)(__shfl(pkv, srcl, 64) & 0x3FFFFu);
          wg[u]    = __shfl(wl, srcl, 64);
          uint2 d  = *(const uint2*)(xt + (size_t)s*DIM + l15*4);  // 4 bf16
          lo[u] = d.x; hi[u] = d.y;
        }
        #pragma unroll
        for (int u = 0; u < 4; u++){
          h0 = fmaf(wg[u], __uint_as_float(lo[u] << 16),          h0);
          h1 = fmaf(wg[u], __uint_as_float(lo[u] & 0xffff0000u),  h1);
          h2 = fmaf(wg[u], __uint_as_float(hi[u] << 16),          h2);
          h3 = fmaf(wg[u], __uint_as_float(hi[u] & 0xffff0000u),  h3);
        }
      }
    }
    // group-wide (16-lane) reductions: xor masks 1,2,4,8 stay inside the group
    float wsum = wsuml;
    #pragma unroll
    for (int off = 8; off > 0; off >>= 1) wsum += __shfl_xor(wsum, off, 64);

    float inv = 1.f / (wsum + 1e-10f);
    float v0 = h0*inv, v1 = h1*inv, v2 = h2*inv, v3 = h3*inv;
    v0 = v0 > 0.f ? v0 : expm1f(v0);
    v1 = v1 > 0.f ? v1 : expm1f(v1);
    v2 = v2 > 0.f ? v2 : expm1f(v2);
    v3 = v3 > 0.f ? v3 : expm1f(v3);
    float ss = v0*v0 + v1*v1 + v2*v2 + v3*v3;
    #pragma unroll
    for (int off = 8; off > 0; off >>= 1) ss += __shfl_xor(ss, off, 64);
    float rinv = 1.f / fmaxf(sqrtf(ss), 1e-12f);
    float x0 = v0*rinv, x1v = v1*rinv, x2 = v2*rinv, x3 = v3*rinv;

    size_t i = (size_t)row*DIM + l15*4;
    if (mode == 0){
      ushort16 st[4] = { (ushort16)((unsigned)f2bs(x0) & 0xffffu),
                         (ushort16)((unsigned)f2bs(x1v) & 0xffffu),
                         (ushort16)((unsigned)f2bs(x2) & 0xffffu),
                         (ushort16)((unsigned)f2bs(x3) & 0xffffu) };
      uint2 pk;
      pk.x = (unsigned)st[0] | ((unsigned)st[1] << 16);
      pk.y = (unsigned)st[2] | ((unsigned)st[3] << 16);
      *(uint2*)(xnext + i) = pk;
    } else {
      float4 nd = *(const float4*)(node + i);
      uint2 xo  = *(const uint2*)(x1 + i);
      float o0 = (nd.x + __uint_as_float(xo.x << 16)         + x0 ) * (1.f/3.f);
      float o1 = (nd.y + __uint_as_float(xo.x & 0xffff0000u) + x1v) * (1.f/3.f);
      float o2 = (nd.z + __uint_as_float(xo.y << 16)         + x2 ) * (1.f/3.f);
      float o3 = (nd.w + __uint_as_float(xo.y & 0xffff0000u) + x3 ) * (1.f/3.f);
      *(float4*)(out + i) = make_float4(o0, o1, o2, o3);
    }
  }
}

extern "C" void kernel_launch(void* const* d_in, const int* in_sizes, int n_in,
                              void* d_out, int out_size, void* d_ws, size_t ws_size,
                              hipStream_t stream){
  const float* node = (const float*)d_in[0];
  const float* W    = (const float*)d_in[1];
  const float* Wr   = (const float*)d_in[2];
  const float* a    = (const float*)d_in[3];
  const float* rel  = (const float*)d_in[4];
  const int*   ei   = (const int*)d_in[5];
  const int*   et   = (const int*)d_in[6];
  const int* src = ei;
  const int* dst = ei + EDGES;
  float* out = (float*)d_out;

  // ---- workspace layout (~48 MB; proven to fit) ----
  char* w = (char*)d_ws;
  size_t off = 0;
  bf16* B  = (bf16*)(w + off); off += (size_t)NND*2;             // 19.2 MB node16/xt1, then xt2
  bf16* XN = (bf16*)(w + off); off += (size_t)NND*2;             // 19.2 MB x1
  unsigned* cse = (unsigned*)(w + off); off += (size_t)EDGES*4;  //  4.8 MB CSR packed
  ushort16* pl = (ushort16*)(w + off); off += (size_t)EDGES*2;   //  2.4 MB per-edge local slot
  int* row_ptr = (int*)(w + off); off += (size_t)(NODES+1)*4;    //  0.6 MB
  int* count   = (int*)(w + off); off += (size_t)NODES*4;        //  0.6 MB
  int* lscan   = (int*)(w + off); off += (size_t)NODES*4;        //  0.6 MB
  int* bsum    = (int*)(w + off); off += (size_t)SCAN_NB*4;      //  2.3 KB
  float* s_src = (float*)(w + off); off += (size_t)NODES*4;      //  0.6 MB
  float* s_dst = (float*)(w + off); off += (size_t)NODES*4;      //  0.6 MB
  float* s_rel = (float*)(w + off); off += 2*NREL*4;

  if (ws_size < off){
    k_sentinel<<<(NND + 255)/256, 256, 0, stream>>>(out, (float)ws_size * 1e-6f);
    return;
  }

  // one-time CSR build (layer-invariant), single atomic pass
  hipMemsetAsync(count, 0, (size_t)NODES*4, stream);
  k_relboth <<<2, 64, 0, stream>>>(Wr, a, rel, s_rel);
  k_inithist<<<4096, 256, 0, stream>>>(node, B, dst, count, pl);
  k_scan1   <<<SCAN_NB, 256, 0, stream>>>(count, lscan, bsum);
  k_scan2   <<<1, 1024, 0, stream>>>(bsum);
  k_scan3   <<<SCAN_NB + 1, 256, 0, stream>>>(lscan, bsum, row_ptr);
  k_build   <<<4096, 256, 0, stream>>>(src, dst, et, pl, row_ptr, cse);

  // layer 0: B(node bf16) -> xt1 in-place in B; x1 -> XN
  k_gemm<<<1024, 256, 0, stream>>>(B, B, W, a, s_src, s_dst);
  k_agg <<<2048, 256, 0, stream>>>(row_ptr, cse, s_src, s_dst, s_rel, B, XN,
                                   node, XN, out, 0);

  // layer 1: XN(x1) -> xt2 in B (keeps x1); fused finale writes out
  k_gemm<<<1024, 256, 0, stream>>>(XN, B, W + DIM*DIM, a + 3*DIM, s_src, s_dst);
  k_agg <<<2048, 256, 0, stream>>>(row_ptr, cse, s_src, s_dst, s_rel + NREL, B, nullptr,
                                   node, XN, out, 1);
}